// Round 18
// baseline (309.130 us; speedup 1.0000x reference)
//
#include <hip/hip_runtime.h>
#include <math.h>

// ---------------------------------------------------------------------------
// BimodalCompressor (round 18)
// r17 -> r18: k_ufused v4 = v2 with 32-row/2-wave/128-thread blocks, grid
// 1250 (was 64-row/4-wave/625): r17 counters showed occupancy grid-limited
// (2.4 blocks/CU). Per-wave math identical to proven v2. All else = r17.
// ---------------------------------------------------------------------------

#define NPTS 40000
#define KNB  32
#define PKP  15
#define SLOPE 0.01f
#define BNEPS 1e-5f
#define INV_N (1.0f/40000.0f)

typedef __attribute__((ext_vector_type(8))) short bf16x8;
typedef __attribute__((ext_vector_type(4))) float f32x4;

__device__ __forceinline__ float lrelu(float x){ return x >= 0.0f ? x : SLOPE*x; }
__device__ __forceinline__ unsigned short f2bf(float f){
  unsigned int b = __float_as_uint(f);
  b += 0x7fffu + ((b>>16)&1u);
  return (unsigned short)(b>>16);
}
__device__ __forceinline__ float bf2f(unsigned short u){
  return __uint_as_float(((unsigned int)u)<<16);
}

// stats layout: see r13 (unchanged)

// --------------------------------------------------------------------------
__global__ __launch_bounds__(256) void k_prep(
    const float* __restrict__ kpw,  const float* __restrict__ pw2,
    const float* __restrict__ aw1,  const float* __restrict__ aw2,
    const float* __restrict__ kw1,  const float* __restrict__ uw1,
    unsigned short* __restrict__ wT,
    unsigned short* __restrict__ posw2B, unsigned short* __restrict__ uw1B,
    const float* __restrict__ cov, const float* __restrict__ pts,
    float* __restrict__ mom){
  __shared__ float sM[63];
  int bid = blockIdx.x, tid = threadIdx.x;
  if (bid < 1728){
    int i = bid*256 + tid;     // < 442368
    const float* src; int K, N, off, li;
    if      (i < 245760){ src=kpw; K=1920; N=128; off=0;      li=i; }
    else if (i < 262144){ src=pw2; K=64;   N=256; off=245760; li=i-245760; }
    else if (i < 294912){ src=aw1; K=128;  N=256; off=262144; li=i-262144; }
    else if (i < 360448){ src=aw2; K=256;  N=256; off=294912; li=i-294912; }
    else if (i < 376832){ src=kw1; K=256;  N=64;  off=360448; li=i-360448; }
    else                { src=uw1; K=512;  N=128; off=376832; li=i-376832; }
    int k = li / N, n = li - k*N;
    wT[(size_t)off + (size_t)n*K + k] = f2bf(src[li]);
  } else if (bid < 1920){
    int i2 = (bid-1728)*256 + tid;     // < 49152
    if (i2 < 16384){
      int f = i2 >> 9, l = (i2 >> 3) & 63, j = i2 & 7;
      int cf = f >> 1, m = f & 1;
      int k = m*32 + (l>>4)*8 + j;
      int col = cf*16 + (l & 15);
      posw2B[i2] = f2bf(pw2[k*256 + col]);
    } else {
      int i3 = i2 - 16384;              // < 32768
      int f = i3 >> 9, l = (i3 >> 3) & 63, j = i3 & 7;
      int cf = f >> 3, m = f & 7;
      int k = m*32 + (l>>4)*8 + j;
      int c = cf*16 + (l & 15);
      uw1B[i3] = f2bf(uw1[k*128 + c]);
    }
  } else {
    // moments: one row per thread
    int lane = tid & 63;
    int row = (bid-1920)*256 + tid;     // < 40960
    if (tid < 63) sM[tid] = 0.0f;
    __syncthreads();
    float c9[9] = {0,0,0,0,0,0,0,0,0};
    float p3[3] = {0,0,0};
    if (row < NPTS){
      #pragma unroll
      for (int i = 0; i < 9; ++i) c9[i] = cov[row*9+i];
      #pragma unroll
      for (int i = 0; i < 3; ++i) p3[i] = pts[row*3+i];
    }
    float vals[63];
    int q = 0;
    #pragma unroll
    for (int i = 0; i < 9; ++i) vals[q++] = c9[i];
    #pragma unroll
    for (int i = 0; i < 9; ++i)
      #pragma unroll
      for (int j = i; j < 9; ++j) vals[q++] = c9[i]*c9[j];
    #pragma unroll
    for (int i = 0; i < 3; ++i) vals[q++] = p3[i];
    #pragma unroll
    for (int i = 0; i < 3; ++i)
      #pragma unroll
      for (int j = i; j < 3; ++j) vals[q++] = p3[i]*p3[j];
    #pragma unroll
    for (int qq = 0; qq < 63; ++qq){
      float v = vals[qq];
      #pragma unroll
      for (int o = 32; o; o >>= 1) v += __shfl_down(v, o, 64);
      if (lane == 0) atomicAdd(&sM[qq], v);
    }
    __syncthreads();
    if (tid < 63) atomicAdd(&mom[tid], sM[tid]);
  }
}

// --------------------------------------------------------------------------
__global__ __launch_bounds__(256) void k_bnsetup(
    const float* __restrict__ preW, const float* __restrict__ preB,
    const float* __restrict__ preG, const float* __restrict__ preBB,
    const float* __restrict__ posW1, const float* __restrict__ posB1,
    const float* __restrict__ posG1, const float* __restrict__ posBB1,
    float* __restrict__ stats){
  int tid = threadIdx.x;
  const float* mom = stats + 2320;
  if (tid < 128){
    int c = tid;
    float wv[9];
    #pragma unroll
    for (int i = 0; i < 9; ++i) wv[i] = preW[i*128+c];
    float b = preB[c];
    float mw = 0.0f;
    #pragma unroll
    for (int i = 0; i < 9; ++i) mw += wv[i]*mom[i];
    mw *= INV_N;
    float quad = 0.0f;
    for (int i = 0; i < 9; ++i)
      for (int j = 0; j < 9; ++j){
        int ii = i < j ? i : j, jj = i < j ? j : i;
        quad += wv[i]*wv[j]*mom[9 + ii*9 - (ii*(ii-1))/2 + (jj-ii)];
      }
    quad *= INV_N;
    float mean = mw + b;
    float var = quad + 2.0f*b*mw + b*b - mean*mean;
    float sc = preG[c]*rsqrtf(var+BNEPS);
    stats[c]     = sc;
    stats[128+c] = preBB[c] - mean*sc + sc*b;
  } else if (tid < 192){
    int c = tid - 128;
    float w0 = posW1[c], w1 = posW1[64+c], w2 = posW1[128+c];
    float b = posB1[c];
    const float* pm = mom + 54;
    const float* pM = mom + 57;
    float mw = (w0*pm[0] + w1*pm[1] + w2*pm[2])*INV_N;
    float quad = (w0*w0*pM[0] + w1*w1*pM[3] + w2*w2*pM[5]
               + 2.0f*(w0*w1*pM[1] + w0*w2*pM[2] + w1*w2*pM[4]))*INV_N;
    float mean = mw + b;
    float var = quad + 2.0f*b*mw + b*b - mean*mean;
    float sc = posG1[c]*rsqrtf(var+BNEPS);
    stats[256+c] = sc;
    stats[320+c] = posBB1[c] - mean*sc + sc*b;
  }
}

// --------------------------------------------------------------------------
__global__ __launch_bounds__(256) void k_feat(
    const float* __restrict__ cov, const float* __restrict__ preW,
    const float* __restrict__ stats, unsigned short* __restrict__ feat,
    float* __restrict__ fsum){
  int tid = threadIdx.x;
  int lane = tid & 63;
  int wv = (blockIdx.x*256 + tid) >> 6;
  int nw = gridDim.x*4;
  int c0 = lane, c1 = lane + 64;
  float w0[9], w1[9];
  #pragma unroll
  for (int i = 0; i < 9; ++i){ w0[i] = preW[i*128+c0]; w1[i] = preW[i*128+c1]; }
  float s0 = stats[c0], h0 = stats[128+c0];
  float s1 = stats[c1], h1 = stats[128+c1];
  for (int n = wv; n < NPTS; n += nw){
    float p0 = 0.0f, p1 = 0.0f;
    #pragma unroll
    for (int i = 0; i < 9; ++i){
      float x = cov[n*9+i];
      p0 += x*w0[i]; p1 += x*w1[i];
    }
    float f0 = lrelu(s0*p0 + h0);
    float f1 = lrelu(s1*p1 + h1);
    feat[(size_t)n*128 + c0] = f2bf(f0);
    feat[(size_t)n*128 + c1] = f2bf(f1);
    float t = f0 + f1;
    #pragma unroll
    for (int o = 32; o; o >>= 1) t += __shfl_down(t, o, 64);
    if (lane == 0) fsum[n] = t;
  }
}

// --------------------------------------------------------------------------
__global__ __launch_bounds__(256) void k_scan(
    const float* __restrict__ pts, const int* __restrict__ nbr,
    const float* __restrict__ kp, const float* __restrict__ fsum,
    float* __restrict__ invn, int* __restrict__ list,
    int* __restrict__ gcount, float ext2){
  __shared__ float sKP[45];
  if (threadIdx.x < 45) sKP[threadIdx.x] = kp[threadIdx.x];
  __syncthreads();
  int wv   = (blockIdx.x*256 + threadIdx.x) >> 6;
  int lane = threadIdx.x & 63;
  int half = lane >> 5;
  int kk   = lane & 31;
  int n    = wv*2 + half;
  float px = pts[n*3+0], py = pts[n*3+1], pz = pts[n*3+2];
  int j = nbr[(size_t)n*KNB + kk];
  float nx = pts[j*3+0] - px;
  float ny = pts[j*3+1] - py;
  float nz = pts[j*3+2] - pz;
  float fs = fsum[j];
  bool anyp = false;
  #pragma unroll
  for (int p = 0; p < PKP; ++p){
    float dx = nx - sKP[p*3+0], dy = ny - sKP[p*3+1], dz = nz - sKP[p*3+2];
    anyp |= (dx*dx + dy*dy + dz*dz < ext2);
  }
  unsigned long long act  = __ballot(anyp);
  unsigned long long good = __ballot(fs > 0.0f);
  unsigned int actH  = half ? (unsigned int)(act  >> 32) : (unsigned int)act;
  unsigned int goodH = half ? (unsigned int)(good >> 32) : (unsigned int)good;
  if (kk == 0){
    int cnt = __popc(goodH);
    invn[n] = 1.0f / (float)(cnt < 1 ? 1 : cnt);
    if (actH){
      int pos = atomicAdd(gcount, 1);
      list[pos] = n;
    }
  }
}

// --------------------------------------------------------------------------
__global__ __launch_bounds__(256) void k_conv_act(
    const float* __restrict__ pts, const int* __restrict__ nbr,
    const float* __restrict__ kp, const unsigned short* __restrict__ feat,
    const unsigned short* __restrict__ kpwT, const float* __restrict__ invn,
    const int* __restrict__ list, const int* __restrict__ gcount,
    unsigned short* __restrict__ kpfc, float ext2, float inv_ext){
  __shared__ float sW[PKP*128];
  __shared__ float sInfl[KNB*16];
  __shared__ unsigned int sPairP[KNB];
  __shared__ float sKP[45];
  __shared__ float sOut[128];
  __shared__ unsigned int sPmask, sPact;
  int tid = threadIdx.x;
  if (tid < 45) sKP[tid] = kp[tid];
  int cnt = *gcount;
  for (int it = blockIdx.x; it < cnt; it += gridDim.x){
    int n = list[it];
    if (tid == 0){ sPmask = 0u; sPact = 0u; }
    for (int i = tid; i < PKP*128; i += 256) sW[i] = 0.0f;
    __syncthreads();
    if (tid < KNB){
      int j = nbr[(size_t)n*KNB + tid];
      float nx = pts[j*3+0] - pts[n*3+0];
      float ny = pts[j*3+1] - pts[n*3+1];
      float nz = pts[j*3+2] - pts[n*3+2];
      unsigned int pm = 0u;
      #pragma unroll
      for (int p = 0; p < PKP; ++p){
        float dx = nx - sKP[p*3+0], dy = ny - sKP[p*3+1], dz = nz - sKP[p*3+2];
        float d2 = dx*dx + dy*dy + dz*dz;
        float infl = 0.0f;
        if (d2 < ext2){ infl = 1.0f - sqrtf(d2)*inv_ext; pm |= (1u << p); }
        sInfl[tid*16 + p] = infl;
      }
      sPairP[tid] = pm;
      if (pm){
        atomicOr(&sPact, 1u << tid);
        atomicOr(&sPmask, pm);
      }
    }
    __syncthreads();
    if (tid < 128){
      int c = tid;
      unsigned int m = sPact;
      while (m){
        int k = __ffs(m) - 1; m &= m - 1;
        int j = nbr[(size_t)n*KNB + k];
        float f = bf2f(feat[(size_t)j*128 + c]);
        unsigned int pp = sPairP[k];
        while (pp){
          int p = __ffs(pp) - 1; pp &= pp - 1;
          sW[p*128 + c] += sInfl[k*16 + p] * f;
        }
      }
    }
    __syncthreads();
    int d = tid & 127, h = tid >> 7;
    float acc = 0.0f;
    unsigned int pm = sPmask;
    while (pm){
      int p = __ffs(pm) - 1; pm &= pm - 1;
      const unsigned short* wp = kpwT + (size_t)d*1920 + p*128 + h*64;
      const float* wsrc = &sW[p*128 + h*64];
      #pragma unroll
      for (int c8 = 0; c8 < 8; ++c8){
        uint4 v = *(const uint4*)(wp + c8*8);
        unsigned int e[4] = {v.x, v.y, v.z, v.w};
        #pragma unroll
        for (int q = 0; q < 4; ++q){
          acc += wsrc[c8*8 + 2*q]     * bf2f((unsigned short)(e[q] & 0xffff));
          acc += wsrc[c8*8 + 2*q + 1] * bf2f((unsigned short)(e[q] >> 16));
        }
      }
    }
    if (h == 0) sOut[d] = acc;
    __syncthreads();
    if (h == 1) kpfc[(size_t)it*128 + d] = f2bf((sOut[d] + acc) * invn[n]);
    __syncthreads();
  }
}

// --------------------------------------------------------------------------
__global__ __launch_bounds__(256) void k_posmom1(
    const float* __restrict__ pts, const float* __restrict__ posW1,
    const float* __restrict__ stats, float* __restrict__ partials){
  __shared__ float sXm[64][65];
  int tid = threadIdx.x;
  int ia[9], ja[9];
  bool va[9];
  #pragma unroll
  for (int q = 0; q < 9; ++q){
    int idx = tid + q*256;
    va[q] = (idx < 2144);
    if (!va[q]){ ia[q] = 0; ja[q] = 0; continue; }
    if (idx < 64){ ia[q] = idx; ja[q] = -1; }
    else {
      int t = idx - 64; int i = 0;
      while (t >= 64 - i){ t -= 64 - i; ++i; }
      ia[q] = i; ja[q] = i + t;
    }
  }
  int c = tid & 63, rg = tid >> 6;
  float w0 = posW1[c], w1v = posW1[64+c], w2v = posW1[128+c];
  float sc1 = stats[256+c], sh1 = stats[320+c];
  int base = blockIdx.x*64;
  for (int r = rg; r < 64; r += 4){
    int row = base + r;
    sXm[r][c] = lrelu(sc1*(pts[row*3+0]*w0 + pts[row*3+1]*w1v
                         + pts[row*3+2]*w2v) + sh1);
  }
  __syncthreads();
  #pragma unroll
  for (int q = 0; q < 9; ++q){
    if (!va[q]) continue;
    float a = 0.0f;
    if (ja[q] < 0){
      for (int r = 0; r < 64; ++r) a += sXm[r][ia[q]];
    } else {
      for (int r = 0; r < 64; ++r) a += sXm[r][ia[q]]*sXm[r][ja[q]];
    }
    partials[(size_t)blockIdx.x*2144 + tid + q*256] = a;
  }
}

// --------------------------------------------------------------------------
__global__ __launch_bounds__(256) void k_posmom2(
    const float* __restrict__ partials, float* __restrict__ pm){
  int c = blockIdx.x*256 + threadIdx.x;
  if (c >= 2144) return;
  float a = 0.0f;
  for (int k = 0; k < 625; ++k) a += partials[(size_t)k*2144 + c];
  pm[c] = a;
}

// --------------------------------------------------------------------------
__global__ __launch_bounds__(256) void k_posbn2a(
    const float* __restrict__ pm, const float* __restrict__ posW2,
    float* __restrict__ U){
  __shared__ float sRow[64];
  int k = blockIdx.x;
  int tid = threadIdx.x;
  if (tid < 64){
    int i = k < tid ? k : tid, j = k < tid ? tid : k;
    int tri = i*64 - (i*(i-1))/2 + (j - i);
    sRow[tid] = pm[64 + tri];
  }
  __syncthreads();
  float a = 0.0f;
  for (int j = 0; j < 64; ++j) a += sRow[j]*posW2[j*256 + tid];
  U[k*256 + tid] = a;
}

// --------------------------------------------------------------------------
__global__ __launch_bounds__(256) void k_posbn2b(
    const float* __restrict__ pm, const float* __restrict__ U,
    const float* __restrict__ posW2, const float* __restrict__ b2,
    const float* __restrict__ g2, const float* __restrict__ bb2,
    float* __restrict__ stats){
  int c = threadIdx.x;
  float mlin = 0.0f, quad = 0.0f;
  for (int k = 0; k < 64; ++k){
    float wkc = posW2[k*256 + c];
    mlin += wkc * pm[k];
    quad += wkc * U[k*256 + c];
  }
  mlin *= INV_N; quad *= INV_N;
  float b = b2[c];
  float mean = mlin + b;
  float var = quad + 2.0f*b*mlin + b*b - mean*mean;
  float sc = g2[c]*rsqrtf(var + BNEPS);
  stats[384+c] = sc;
  stats[640+c] = bb2[c] - mean*sc + sc*b;
}

// --------------------------------------------------------------------------
// ufused v4: v2 math with 32-row / 2-wave / 128-thread blocks, grid 1250.
// LDS 23.5KB; per-wave code identical to v2 (u1 bit-identical).
// --------------------------------------------------------------------------
__global__ __launch_bounds__(128) void k_ufused(
    const float* __restrict__ pts, const float* __restrict__ posW1,
    const float* __restrict__ stats, const unsigned short* __restrict__ posw2B,
    const unsigned short* __restrict__ uw1B, const float* __restrict__ ub_eff,
    unsigned short* __restrict__ u1, float* __restrict__ st2048){
  __shared__ __align__(16) unsigned short sX[2048];    // 4KB: [32][64] swz / epi
  __shared__ __align__(16) unsigned short sY[8192];    // 16KB: [32][256] swz
  __shared__ float sC[512];
  __shared__ float sSum[128], sSq[128];
  int tid = threadIdx.x;
  int row0 = blockIdx.x*32;
  int w = tid >> 6, l = tid & 63;
  for (int i = tid; i < 512; i += 128) sC[i] = stats[384 + i];
  sSum[tid] = 0.0f; sSq[tid] = 0.0f;
  {
    int c = tid & 63, rg = tid >> 6;          // 2 row-groups
    float w0 = posW1[c], w1v = posW1[64+c], w2v = posW1[128+c];
    float sc1 = stats[256+c], sh1 = stats[320+c];
    for (int r = rg; r < 32; r += 2){
      int row = row0 + r;
      float f = lrelu(sc1*(pts[row*3+0]*w0 + pts[row*3+1]*w1v
                         + pts[row*3+2]*w2v) + sh1);
      *(unsigned short*)((char*)sX + ((r*128 + c*2) ^ ((r&7)<<4))) = f2bf(f);
    }
  }
  __syncthreads();
  int rowA = w*16 + (l & 15);                 // 0..31
  bf16x8 af0 = *(const bf16x8*)((const char*)sX +
               ((rowA*128 + ((l>>4)*8)*2) ^ ((rowA&7)<<4)));
  bf16x8 af1 = *(const bf16x8*)((const char*)sX +
               ((rowA*128 + (32+(l>>4)*8)*2) ^ ((rowA&7)<<4)));
  #pragma unroll
  for (int c4 = 0; c4 < 4; ++c4){
    bf16x8 b0[4], b1[4];
    #pragma unroll
    for (int j = 0; j < 4; ++j){
      int cf = c4*4 + j;
      b0[j] = *(const bf16x8*)(posw2B + (size_t)(cf*2+0)*512 + l*8);
      b1[j] = *(const bf16x8*)(posw2B + (size_t)(cf*2+1)*512 + l*8);
    }
    f32x4 acc[4] = {};
    #pragma unroll
    for (int j = 0; j < 4; ++j){
      acc[j] = __builtin_amdgcn_mfma_f32_16x16x32_bf16(af0, b0[j], acc[j], 0,0,0);
      acc[j] = __builtin_amdgcn_mfma_f32_16x16x32_bf16(af1, b1[j], acc[j], 0,0,0);
    }
    #pragma unroll
    for (int j = 0; j < 4; ++j){
      int col = (c4*4+j)*16 + (l & 15);
      float sc = sC[col], sh = sC[256+col];
      #pragma unroll
      for (int r = 0; r < 4; ++r){
        int row = w*16 + (l >> 4)*4 + r;
        float y = lrelu(sc*acc[j][r] + sh);
        *(unsigned short*)((char*)sY + ((row*512 + col*2) ^ ((row&7)<<4))) = f2bf(y);
      }
    }
  }
  __syncthreads();
  #pragma unroll
  for (int c4 = 0; c4 < 2; ++c4){
    f32x4 acc[4] = {};
    #pragma unroll
    for (int m = 0; m < 8; ++m){
      int ka = m*32 + (l >> 4)*8;
      bf16x8 af = *(const bf16x8*)((const char*)sY +
                  ((rowA*512 + ka*2) ^ ((rowA&7)<<4)));
      bf16x8 bb[4];
      #pragma unroll
      for (int j = 0; j < 4; ++j)
        bb[j] = *(const bf16x8*)(uw1B + (size_t)((c4*4+j)*8+m)*512 + l*8);
      #pragma unroll
      for (int j = 0; j < 4; ++j)
        acc[j] = __builtin_amdgcn_mfma_f32_16x16x32_bf16(af, bb[j], acc[j], 0,0,0);
    }
    #pragma unroll
    for (int j = 0; j < 4; ++j){
      int colh = j*16 + (l & 15);
      int col  = c4*64 + colh;
      float bj = ub_eff[col];
      float cs = 0.0f, cq = 0.0f;
      #pragma unroll
      for (int r = 0; r < 4; ++r){
        int row = w*16 + (l >> 4)*4 + r;
        float v = acc[j][r] + bj;
        *(unsigned short*)((char*)sX + ((row*128 + colh*2) ^ ((row&7)<<4))) = f2bf(v);
        cs += v; cq += v*v;
      }
      atomicAdd(&sSum[col], cs);
      atomicAdd(&sSq[col],  cq);
    }
    __syncthreads();
    #pragma unroll
    for (int ps = 0; ps < 2; ++ps){
      int idx = ps*128 + tid;                 // < 256 = 32 rows x 8 groups
      int row = idx >> 3, g = idx & 7;
      uint4 v = *(const uint4*)((const char*)sX + ((row*128 + g*16) ^ ((row&7)<<4)));
      *(uint4*)(u1 + (size_t)(row0+row)*128 + c4*64 + g*8) = v;
    }
    __syncthreads();
  }
  atomicAdd(&st2048[tid],     sSum[tid]);
  atomicAdd(&st2048[128+tid], sSq[tid]);
}

// --------------------------------------------------------------------------
__global__ __launch_bounds__(256) void k_rowgemm(
    const unsigned short* __restrict__ X,
    const float* __restrict__ st, const float* __restrict__ g,
    const float* __restrict__ bb, int K, int norm,
    const unsigned short* __restrict__ Wt, const float* __restrict__ bias,
    int NOUT, unsigned short* __restrict__ Y, float* __restrict__ statsOut,
    const int* __restrict__ list, const int* __restrict__ gcount){
  __shared__ float xs[256];
  __shared__ float sSc[256], sSh[256];
  int tid = threadIdx.x;
  if (norm && tid < K){
    float s = st[tid], q = st[K+tid];
    float mean = s*INV_N, var = q*INV_N - mean*mean;
    float sc = g[tid]*rsqrtf(var+BNEPS);
    sSc[tid] = sc; sSh[tid] = bb[tid] - mean*sc;
  }
  __syncthreads();
  int cnt = *gcount;
  float rs = 0.0f, rq = 0.0f;
  for (int it = blockIdx.x; it < cnt; it += gridDim.x){
    if (tid < K){
      float xv = bf2f(X[(size_t)it*K + tid]);
      if (norm) xv = lrelu(xv*sSc[tid] + sSh[tid]);
      xs[tid] = xv;
    }
    __syncthreads();
    if (tid < NOUT){
      float acc = bias[tid];
      const unsigned short* wp = Wt + (size_t)tid*K;
      for (int k8 = 0; k8 < K; k8 += 8){
        uint4 v = *(const uint4*)(wp + k8);
        unsigned int e[4] = {v.x, v.y, v.z, v.w};
        #pragma unroll
        for (int q = 0; q < 4; ++q){
          acc += xs[k8+2*q]   * bf2f((unsigned short)(e[q] & 0xffff));
          acc += xs[k8+2*q+1] * bf2f((unsigned short)(e[q] >> 16));
        }
      }
      Y[(size_t)it*NOUT + tid] = f2bf(acc);
      rs += acc; rq += acc*acc;
    }
    __syncthreads();
  }
  if (tid < NOUT && rs != 0.0f){
    atomicAdd(&statsOut[tid],      rs);
    atomicAdd(&statsOut[NOUT+tid], rq);
  }
}

// --------------------------------------------------------------------------
__global__ __launch_bounds__(256) void k_const1(
    const float* __restrict__ b1, const float* __restrict__ g1,
    const float* __restrict__ bb1, const unsigned short* __restrict__ aggw2T,
    const float* __restrict__ b2, float* __restrict__ st896,
    float* __restrict__ v2, const int* __restrict__ gcount){
  __shared__ float sX[256];
  int tid = threadIdx.x;
  float fN = (float)(NPTS - *gcount);
  float s = b1[tid];
  st896[tid]     += fN*s;
  st896[256+tid] += fN*s*s;
  float su = st896[tid], sq = st896[256+tid];
  float mean = su*INV_N, var = sq*INV_N - mean*mean;
  float sc = g1[tid]*rsqrtf(var+BNEPS);
  sX[tid] = lrelu(s*sc + bb1[tid] - mean*sc);
  __syncthreads();
  float acc = b2[tid];
  const unsigned short* wp = aggw2T + (size_t)tid*256;
  for (int k8 = 0; k8 < 256; k8 += 8){
    uint4 v = *(const uint4*)(wp + k8);
    unsigned int e[4] = {v.x, v.y, v.z, v.w};
    #pragma unroll
    for (int q = 0; q < 4; ++q){
      acc += sX[k8+2*q]   * bf2f((unsigned short)(e[q] & 0xffff));
      acc += sX[k8+2*q+1] * bf2f((unsigned short)(e[q] >> 16));
    }
  }
  v2[tid] = acc;
}

// --------------------------------------------------------------------------
__global__ __launch_bounds__(256) void k_const2(
    const float* __restrict__ v2, const float* __restrict__ g2,
    const float* __restrict__ bb2, const unsigned short* __restrict__ keepw1T,
    const float* __restrict__ kb1, const unsigned short* __restrict__ uw1T,
    const float* __restrict__ ub1, float* __restrict__ st1408,
    float* __restrict__ v3, float* __restrict__ ub_eff,
    const int* __restrict__ gcount){
  __shared__ float sX[256];
  int tid = threadIdx.x;
  float fN = (float)(NPTS - *gcount);
  float s = v2[tid];
  st1408[tid]     += fN*s;
  st1408[256+tid] += fN*s*s;
  float su = st1408[tid], sq = st1408[256+tid];
  float mean = su*INV_N, var = sq*INV_N - mean*mean;
  float sc = g2[tid]*rsqrtf(var+BNEPS);
  sX[tid] = lrelu(s*sc + bb2[tid] - mean*sc);
  __syncthreads();
  if (tid < 64){
    float acc = kb1[tid];
    const unsigned short* wp = keepw1T + (size_t)tid*256;
    for (int k8 = 0; k8 < 256; k8 += 8){
      uint4 v = *(const uint4*)(wp + k8);
      unsigned int e[4] = {v.x, v.y, v.z, v.w};
      #pragma unroll
      for (int q = 0; q < 4; ++q){
        acc += sX[k8+2*q]   * bf2f((unsigned short)(e[q] & 0xffff));
        acc += sX[k8+2*q+1] * bf2f((unsigned short)(e[q] >> 16));
      }
    }
    v3[tid] = acc;
  } else if (tid < 192){
    int c = tid - 64;
    float acc = ub1[c];
    const unsigned short* wp = uw1T + (size_t)c*512 + 256;
    for (int k8 = 0; k8 < 256; k8 += 8){
      uint4 v = *(const uint4*)(wp + k8);
      unsigned int e[4] = {v.x, v.y, v.z, v.w};
      #pragma unroll
      for (int q = 0; q < 4; ++q){
        acc += sX[k8+2*q]   * bf2f((unsigned short)(e[q] & 0xffff));
        acc += sX[k8+2*q+1] * bf2f((unsigned short)(e[q] >> 16));
      }
    }
    ub_eff[c] = acc;
  }
}

// --------------------------------------------------------------------------
__global__ __launch_bounds__(64) void k_const3(
    const float* __restrict__ v3, const float* __restrict__ g3,
    const float* __restrict__ bb3, const float* __restrict__ kw2,
    const float* __restrict__ kb2, float* __restrict__ st1920,
    float* __restrict__ s3out, const int* __restrict__ gcount){
  int tid = threadIdx.x;
  float fN = (float)(NPTS - *gcount);
  float s = v3[tid];
  st1920[tid]    += fN*s;
  st1920[64+tid] += fN*s*s;
  float su = st1920[tid], sq = st1920[64+tid];
  float mean = su*INV_N, var = sq*INV_N - mean*mean;
  float sc = g3[tid]*rsqrtf(var+BNEPS);
  float h = lrelu(s*sc + bb3[tid] - mean*sc) * kw2[tid];
  #pragma unroll
  for (int o = 32; o; o >>= 1) h += __shfl_down(h, o, 64);
  if (tid == 0) s3out[0] = 1.0f/(1.0f + expf(-(h + kb2[0])));
}

// --------------------------------------------------------------------------
__global__ __launch_bounds__(256) void k_udelta_keep(
    const unsigned short* __restrict__ a2c, const float* __restrict__ st1408,
    const float* __restrict__ g2, const float* __restrict__ bb2,
    const unsigned short* __restrict__ uw1T, const float* __restrict__ ub1,
    const float* __restrict__ ub_eff, unsigned short* __restrict__ u1,
    float* __restrict__ st2048,
    const unsigned short* __restrict__ k1c, const float* __restrict__ st1920,
    const float* __restrict__ g3, const float* __restrict__ b3,
    const float* __restrict__ kw2, const float* __restrict__ kb2,
    float* __restrict__ out,
    const int* __restrict__ list, const int* __restrict__ gcount){
  __shared__ float sX[256];
  __shared__ float sSc[256], sSh[256];
  int tid = threadIdx.x;
  int cnt = *gcount;
  if (blockIdx.x < 128){
    {
      float su = st1408[tid], sq = st1408[256+tid];
      float mean = su*INV_N, var = sq*INV_N - mean*mean;
      float sc = g2[tid]*rsqrtf(var+BNEPS);
      sSc[tid] = sc; sSh[tid] = bb2[tid] - mean*sc;
    }
    __syncthreads();
    for (int it = blockIdx.x; it < cnt; it += 128){
      int n = list[it];
      sX[tid] = lrelu(bf2f(a2c[(size_t)it*256 + tid])*sSc[tid] + sSh[tid]);
      __syncthreads();
      if (tid < 128){
        float acc = ub1[tid] - ub_eff[tid];
        const unsigned short* wp = uw1T + (size_t)tid*512 + 256;
        for (int k8 = 0; k8 < 256; k8 += 8){
          uint4 v = *(const uint4*)(wp + k8);
          unsigned int e[4] = {v.x, v.y, v.z, v.w};
          #pragma unroll
          for (int q = 0; q < 4; ++q){
            acc += sX[k8+2*q]   * bf2f((unsigned short)(e[q] & 0xffff));
            acc += sX[k8+2*q+1] * bf2f((unsigned short)(e[q] >> 16));
          }
        }
        float old = bf2f(u1[(size_t)n*128 + tid]);
        float neu = old + acc;
        u1[(size_t)n*128 + tid] = f2bf(neu);
        atomicAdd(&st2048[tid],     neu - old);
        atomicAdd(&st2048[128+tid], neu*neu - old*old);
      }
      __syncthreads();
    }
  } else {
    int lane = tid & 63;
    int wv = (blockIdx.x - 128)*4 + (tid >> 6);
    float su = st1920[lane], sq = st1920[64+lane];
    float mean = su*INV_N, var = sq*INV_N - mean*mean;
    float sc = g3[lane]*rsqrtf(var+BNEPS);
    float sh = b3[lane] - mean*sc;
    float w2v = kw2[lane];
    for (int it = wv; it < cnt; it += 128){
      float h = lrelu(bf2f(k1c[(size_t)it*64 + lane])*sc + sh) * w2v;
      #pragma unroll
      for (int o = 32; o; o >>= 1) h += __shfl_down(h, o, 64);
      if (lane == 0) out[list[it]] = 1.0f/(1.0f + expf(-(h + kb2[0])));
    }
  }
}

// --------------------------------------------------------------------------
__global__ __launch_bounds__(256) void k_uhead_out(
    const unsigned short* __restrict__ u1, const float* __restrict__ st2048,
    const float* __restrict__ g, const float* __restrict__ b,
    const float* __restrict__ w2, const float* __restrict__ b2,
    const int* __restrict__ nbr, const float* __restrict__ s3p,
    float* __restrict__ out){
  __shared__ float sSc[128], sSh[128], sW2[128];
  int tid = threadIdx.x;
  if (blockIdx.x >= 2500){
    int i = (blockIdx.x - 2500)*256 + tid;     // < 320000
    if (i < NPTS) out[i] = s3p[0];
    int4 v = ((const int4*)nbr)[i];
    ((float4*)(out + 2*NPTS))[i] =
        make_float4((float)v.x,(float)v.y,(float)v.z,(float)v.w);
    return;
  }
  if (tid < 128){
    float su = st2048[tid], sq = st2048[128+tid];
    float mean = su*INV_N, var = sq*INV_N - mean*mean;
    float sc = g[tid]*rsqrtf(var+BNEPS);
    sSc[tid] = sc; sSh[tid] = b[tid] - mean*sc;
    sW2[tid] = w2[tid];
  }
  __syncthreads();
  int lane = tid & 63, w = tid >> 6;
  for (int n = blockIdx.x*4 + w; n < NPTS; n += 10000){
    unsigned int v = *(const unsigned int*)(u1 + (size_t)n*128 + lane*2);
    int c0 = lane*2, c1 = c0 + 1;
    float h = lrelu(bf2f((unsigned short)(v & 0xffff))*sSc[c0] + sSh[c0])*sW2[c0]
            + lrelu(bf2f((unsigned short)(v >> 16))*sSc[c1] + sSh[c1])*sW2[c1];
    #pragma unroll
    for (int o = 32; o; o >>= 1) h += __shfl_down(h, o, 64);
    if (lane == 0) out[NPTS + n] = 1.0f/(1.0f + expf(-(h + b2[0])));
  }
}

// --------------------------------------------------------------------------
extern "C" void kernel_launch(void* const* d_in, const int* in_sizes, int n_in,
                              void* d_out, int out_size, void* d_ws, size_t ws_size,
                              hipStream_t stream) {
  const float* pts    = (const float*)d_in[0];
  const float* cov    = (const float*)d_in[1];
  const int*   nbr    = (const int*)  d_in[2];
  const float* pre_w  = (const float*)d_in[3];
  const float* pre_b  = (const float*)d_in[4];
  const float* pre_g  = (const float*)d_in[5];
  const float* pre_bb = (const float*)d_in[6];
  const float* kp     = (const float*)d_in[7];
  const float* kpw    = (const float*)d_in[8];
  const float* pos_w1 = (const float*)d_in[9];
  const float* pos_b1 = (const float*)d_in[10];
  const float* pos_g1 = (const float*)d_in[11];
  const float* pos_bb1= (const float*)d_in[12];
  const float* pos_w2 = (const float*)d_in[13];
  const float* pos_b2 = (const float*)d_in[14];
  const float* pos_g2 = (const float*)d_in[15];
  const float* pos_bb2= (const float*)d_in[16];
  const float* agg_w1 = (const float*)d_in[17];
  const float* agg_b1 = (const float*)d_in[18];
  const float* agg_g1 = (const float*)d_in[19];
  const float* agg_bb1= (const float*)d_in[20];
  const float* agg_w2 = (const float*)d_in[21];
  const float* agg_b2 = (const float*)d_in[22];
  const float* agg_g2 = (const float*)d_in[23];
  const float* agg_bb2= (const float*)d_in[24];
  const float* keep_w1= (const float*)d_in[25];
  const float* keep_b1= (const float*)d_in[26];
  const float* keep_g = (const float*)d_in[27];
  const float* keep_bb= (const float*)d_in[28];
  const float* keep_w2= (const float*)d_in[29];
  const float* keep_b2= (const float*)d_in[30];
  const float* uniq_w1= (const float*)d_in[31];
  const float* uniq_b1= (const float*)d_in[32];
  const float* uniq_g = (const float*)d_in[33];
  const float* uniq_bb= (const float*)d_in[34];
  const float* uniq_w2= (const float*)d_in[35];
  const float* uniq_b2= (const float*)d_in[36];

  float* out = (float*)d_out;

  // ---- ws layout ----
  char* wsb = (char*)d_ws;
  size_t off = 0;
  float* stats = (float*)(wsb + off); off += 8192*4;
  int*   gcount = (int*)(stats + 2304);
  float* s3     = stats + 2305;
  float* mom    = stats + 2320;
  float* v2     = stats + 2384;
  float* v3     = stats + 2640;
  float* ub_eff = stats + 2704;
  float* pm     = stats + 2832;              // 2144 floats (X moments)
  float* U      = (float*)(wsb + off); off += 16384*4;
  float* partials = (float*)(wsb + off); off += (size_t)625*2144*4;  // 5.36MB
  unsigned short* wT = (unsigned short*)(wsb + off); off += (size_t)442368*2;
  unsigned short* kpwT   = wT;
  unsigned short* aggw1T = wT + 262144;
  unsigned short* aggw2T = wT + 294912;
  unsigned short* keepw1T= wT + 360448;
  unsigned short* uniqw1T= wT + 376832;
  unsigned short* posw2B = (unsigned short*)(wsb + off); off += (size_t)16384*2;
  unsigned short* uw1B   = (unsigned short*)(wsb + off); off += (size_t)32768*2;
  float* fsum = (float*)(wsb + off); off += (size_t)NPTS*4;
  float* invn = (float*)(wsb + off); off += (size_t)NPTS*4;
  int*   list = (int*)  (wsb + off); off += (size_t)NPTS*4;
  unsigned short* feat = (unsigned short*)(wsb + off); off += (size_t)NPTS*128*2;
  unsigned short* kpfc = (unsigned short*)(wsb + off); off += (size_t)NPTS*128*2;
  unsigned short* a1c  = (unsigned short*)(wsb + off); off += (size_t)NPTS*256*2;
  unsigned short* a2c  = (unsigned short*)(wsb + off); off += (size_t)NPTS*256*2;
  unsigned short* k1c  = (unsigned short*)(wsb + off); off += (size_t)NPTS*64*2;
  unsigned short* u1   = (unsigned short*)(wsb + off); off += (size_t)NPTS*128*2;

  const double kpe = 1.0 / (cbrt(15.0) - 1.0) * 1.5;   // KP_EXTENT
  const float inv_ext = (float)(1.0 / kpe);
  const float ext2 = (float)(kpe * kpe);

  hipMemsetAsync(stats, 0, 2832*sizeof(float), stream);

  // prep: transposes + frag-pack + input moments
  k_prep<<<2080, 256, 0, stream>>>(kpw, pos_w2, agg_w1, agg_w2, keep_w1,
                                   uniq_w1, wT, posw2B, uw1B, cov, pts, mom);
  k_bnsetup<<<1, 256, 0, stream>>>(pre_w, pre_b, pre_g, pre_bb,
                                   pos_w1, pos_b1, pos_g1, pos_bb1, stats);
  k_feat<<<2500, 256, 0, stream>>>(cov, pre_w, stats, feat, fsum);
  k_scan<<<5000, 256, 0, stream>>>(pts, nbr, kp, fsum, invn, list, gcount, ext2);
  k_conv_act<<<1024, 256, 0, stream>>>(pts, nbr, kp, feat, kpwT, invn,
                                       list, gcount, kpfc, ext2, inv_ext);

  // pos-branch closed-form bn2 (two-stage deterministic moments)
  k_posmom1<<<625, 256, 0, stream>>>(pts, pos_w1, stats, partials);
  k_posmom2<<<9, 256, 0, stream>>>(partials, pm);
  k_posbn2a<<<64, 256, 0, stream>>>(pm, pos_w2, U);
  k_posbn2b<<<1, 256, 0, stream>>>(pm, U, pos_w2, pos_b2, pos_g2, pos_bb2, stats);

  // sparse agg chain
  k_rowgemm<<<256, 256, 0, stream>>>(kpfc, nullptr, nullptr, nullptr, 128, 0,
                                     aggw1T, agg_b1, 256, a1c, stats + 896,
                                     list, gcount);
  k_const1<<<1, 256, 0, stream>>>(agg_b1, agg_g1, agg_bb1, aggw2T, agg_b2,
                                  stats + 896, v2, gcount);
  k_rowgemm<<<256, 256, 0, stream>>>(a1c, stats + 896, agg_g1, agg_bb1, 256, 1,
                                     aggw2T, agg_b2, 256, a2c, stats + 1408,
                                     list, gcount);
  k_const2<<<1, 256, 0, stream>>>(v2, agg_g2, agg_bb2, keepw1T, keep_b1,
                                  uniqw1T, uniq_b1, stats + 1408, v3, ub_eff,
                                  gcount);
  k_rowgemm<<<256, 256, 0, stream>>>(a2c, stats + 1408, agg_g2, agg_bb2, 256, 1,
                                     keepw1T, keep_b1, 64, k1c, stats + 1920,
                                     list, gcount);
  k_const3<<<1, 64, 0, stream>>>(v3, keep_g, keep_bb, keep_w2, keep_b2,
                                 stats + 1920, s3, gcount);

  // uniq: fused pts->X->p2->bn2->u1; then active delta + keepact
  k_ufused<<<1250, 128, 0, stream>>>(pts, pos_w1, stats, posw2B, uw1B,
                                     ub_eff, u1, stats + 2048);
  k_udelta_keep<<<160, 256, 0, stream>>>(a2c, stats + 1408, agg_g2, agg_bb2,
                                         uniqw1T, uniq_b1, ub_eff, u1,
                                         stats + 2048, k1c, stats + 1920,
                                         keep_g, keep_bb, keep_w2, keep_b2,
                                         out, list, gcount);
  // uhead + match-fill + idx passthrough
  k_uhead_out<<<3750, 256, 0, stream>>>(u1, stats + 2048, uniq_g, uniq_bb,
                                        uniq_w2, uniq_b2, nbr, s3, out);
}

// Round 19
// 298.533 us; speedup vs baseline: 1.0355x; 1.0355x over previous
//
#include <hip/hip_runtime.h>
#include <math.h>

// ---------------------------------------------------------------------------
// BimodalCompressor (round 19 = r17 config, best known: 297.9us).
// r18 post-mortem: v4 32-row geometry null/worse (59us, occupancy unchanged
// -> per-wave latency floor, only 2.4 waves/SIMD machine-wide). Locked in v2.
// ---------------------------------------------------------------------------

#define NPTS 40000
#define KNB  32
#define PKP  15
#define SLOPE 0.01f
#define BNEPS 1e-5f
#define INV_N (1.0f/40000.0f)

typedef __attribute__((ext_vector_type(8))) short bf16x8;
typedef __attribute__((ext_vector_type(4))) float f32x4;

__device__ __forceinline__ float lrelu(float x){ return x >= 0.0f ? x : SLOPE*x; }
__device__ __forceinline__ unsigned short f2bf(float f){
  unsigned int b = __float_as_uint(f);
  b += 0x7fffu + ((b>>16)&1u);
  return (unsigned short)(b>>16);
}
__device__ __forceinline__ float bf2f(unsigned short u){
  return __uint_as_float(((unsigned int)u)<<16);
}

// stats layout: see r13 (unchanged)

// --------------------------------------------------------------------------
__global__ __launch_bounds__(256) void k_prep(
    const float* __restrict__ kpw,  const float* __restrict__ pw2,
    const float* __restrict__ aw1,  const float* __restrict__ aw2,
    const float* __restrict__ kw1,  const float* __restrict__ uw1,
    unsigned short* __restrict__ wT,
    unsigned short* __restrict__ posw2B, unsigned short* __restrict__ uw1B,
    const float* __restrict__ cov, const float* __restrict__ pts,
    float* __restrict__ mom){
  __shared__ float sM[63];
  int bid = blockIdx.x, tid = threadIdx.x;
  if (bid < 1728){
    int i = bid*256 + tid;     // < 442368
    const float* src; int K, N, off, li;
    if      (i < 245760){ src=kpw; K=1920; N=128; off=0;      li=i; }
    else if (i < 262144){ src=pw2; K=64;   N=256; off=245760; li=i-245760; }
    else if (i < 294912){ src=aw1; K=128;  N=256; off=262144; li=i-262144; }
    else if (i < 360448){ src=aw2; K=256;  N=256; off=294912; li=i-294912; }
    else if (i < 376832){ src=kw1; K=256;  N=64;  off=360448; li=i-360448; }
    else                { src=uw1; K=512;  N=128; off=376832; li=i-376832; }
    int k = li / N, n = li - k*N;
    wT[(size_t)off + (size_t)n*K + k] = f2bf(src[li]);
  } else if (bid < 1920){
    int i2 = (bid-1728)*256 + tid;     // < 49152
    if (i2 < 16384){
      int f = i2 >> 9, l = (i2 >> 3) & 63, j = i2 & 7;
      int cf = f >> 1, m = f & 1;
      int k = m*32 + (l>>4)*8 + j;
      int col = cf*16 + (l & 15);
      posw2B[i2] = f2bf(pw2[k*256 + col]);
    } else {
      int i3 = i2 - 16384;              // < 32768
      int f = i3 >> 9, l = (i3 >> 3) & 63, j = i3 & 7;
      int cf = f >> 3, m = f & 7;
      int k = m*32 + (l>>4)*8 + j;
      int c = cf*16 + (l & 15);
      uw1B[i3] = f2bf(uw1[k*128 + c]);
    }
  } else {
    // moments: one row per thread
    int lane = tid & 63;
    int row = (bid-1920)*256 + tid;     // < 40960
    if (tid < 63) sM[tid] = 0.0f;
    __syncthreads();
    float c9[9] = {0,0,0,0,0,0,0,0,0};
    float p3[3] = {0,0,0};
    if (row < NPTS){
      #pragma unroll
      for (int i = 0; i < 9; ++i) c9[i] = cov[row*9+i];
      #pragma unroll
      for (int i = 0; i < 3; ++i) p3[i] = pts[row*3+i];
    }
    float vals[63];
    int q = 0;
    #pragma unroll
    for (int i = 0; i < 9; ++i) vals[q++] = c9[i];
    #pragma unroll
    for (int i = 0; i < 9; ++i)
      #pragma unroll
      for (int j = i; j < 9; ++j) vals[q++] = c9[i]*c9[j];
    #pragma unroll
    for (int i = 0; i < 3; ++i) vals[q++] = p3[i];
    #pragma unroll
    for (int i = 0; i < 3; ++i)
      #pragma unroll
      for (int j = i; j < 3; ++j) vals[q++] = p3[i]*p3[j];
    #pragma unroll
    for (int qq = 0; qq < 63; ++qq){
      float v = vals[qq];
      #pragma unroll
      for (int o = 32; o; o >>= 1) v += __shfl_down(v, o, 64);
      if (lane == 0) atomicAdd(&sM[qq], v);
    }
    __syncthreads();
    if (tid < 63) atomicAdd(&mom[tid], sM[tid]);
  }
}

// --------------------------------------------------------------------------
__global__ __launch_bounds__(256) void k_bnsetup(
    const float* __restrict__ preW, const float* __restrict__ preB,
    const float* __restrict__ preG, const float* __restrict__ preBB,
    const float* __restrict__ posW1, const float* __restrict__ posB1,
    const float* __restrict__ posG1, const float* __restrict__ posBB1,
    float* __restrict__ stats){
  int tid = threadIdx.x;
  const float* mom = stats + 2320;
  if (tid < 128){
    int c = tid;
    float wv[9];
    #pragma unroll
    for (int i = 0; i < 9; ++i) wv[i] = preW[i*128+c];
    float b = preB[c];
    float mw = 0.0f;
    #pragma unroll
    for (int i = 0; i < 9; ++i) mw += wv[i]*mom[i];
    mw *= INV_N;
    float quad = 0.0f;
    for (int i = 0; i < 9; ++i)
      for (int j = 0; j < 9; ++j){
        int ii = i < j ? i : j, jj = i < j ? j : i;
        quad += wv[i]*wv[j]*mom[9 + ii*9 - (ii*(ii-1))/2 + (jj-ii)];
      }
    quad *= INV_N;
    float mean = mw + b;
    float var = quad + 2.0f*b*mw + b*b - mean*mean;
    float sc = preG[c]*rsqrtf(var+BNEPS);
    stats[c]     = sc;
    stats[128+c] = preBB[c] - mean*sc + sc*b;
  } else if (tid < 192){
    int c = tid - 128;
    float w0 = posW1[c], w1 = posW1[64+c], w2 = posW1[128+c];
    float b = posB1[c];
    const float* pm = mom + 54;
    const float* pM = mom + 57;
    float mw = (w0*pm[0] + w1*pm[1] + w2*pm[2])*INV_N;
    float quad = (w0*w0*pM[0] + w1*w1*pM[3] + w2*w2*pM[5]
               + 2.0f*(w0*w1*pM[1] + w0*w2*pM[2] + w1*w2*pM[4]))*INV_N;
    float mean = mw + b;
    float var = quad + 2.0f*b*mw + b*b - mean*mean;
    float sc = posG1[c]*rsqrtf(var+BNEPS);
    stats[256+c] = sc;
    stats[320+c] = posBB1[c] - mean*sc + sc*b;
  }
}

// --------------------------------------------------------------------------
__global__ __launch_bounds__(256) void k_feat(
    const float* __restrict__ cov, const float* __restrict__ preW,
    const float* __restrict__ stats, unsigned short* __restrict__ feat,
    float* __restrict__ fsum){
  int tid = threadIdx.x;
  int lane = tid & 63;
  int wv = (blockIdx.x*256 + tid) >> 6;
  int nw = gridDim.x*4;
  int c0 = lane, c1 = lane + 64;
  float w0[9], w1[9];
  #pragma unroll
  for (int i = 0; i < 9; ++i){ w0[i] = preW[i*128+c0]; w1[i] = preW[i*128+c1]; }
  float s0 = stats[c0], h0 = stats[128+c0];
  float s1 = stats[c1], h1 = stats[128+c1];
  for (int n = wv; n < NPTS; n += nw){
    float p0 = 0.0f, p1 = 0.0f;
    #pragma unroll
    for (int i = 0; i < 9; ++i){
      float x = cov[n*9+i];
      p0 += x*w0[i]; p1 += x*w1[i];
    }
    float f0 = lrelu(s0*p0 + h0);
    float f1 = lrelu(s1*p1 + h1);
    feat[(size_t)n*128 + c0] = f2bf(f0);
    feat[(size_t)n*128 + c1] = f2bf(f1);
    float t = f0 + f1;
    #pragma unroll
    for (int o = 32; o; o >>= 1) t += __shfl_down(t, o, 64);
    if (lane == 0) fsum[n] = t;
  }
}

// --------------------------------------------------------------------------
__global__ __launch_bounds__(256) void k_scan(
    const float* __restrict__ pts, const int* __restrict__ nbr,
    const float* __restrict__ kp, const float* __restrict__ fsum,
    float* __restrict__ invn, int* __restrict__ list,
    int* __restrict__ gcount, float ext2){
  __shared__ float sKP[45];
  if (threadIdx.x < 45) sKP[threadIdx.x] = kp[threadIdx.x];
  __syncthreads();
  int wv   = (blockIdx.x*256 + threadIdx.x) >> 6;
  int lane = threadIdx.x & 63;
  int half = lane >> 5;
  int kk   = lane & 31;
  int n    = wv*2 + half;
  float px = pts[n*3+0], py = pts[n*3+1], pz = pts[n*3+2];
  int j = nbr[(size_t)n*KNB + kk];
  float nx = pts[j*3+0] - px;
  float ny = pts[j*3+1] - py;
  float nz = pts[j*3+2] - pz;
  float fs = fsum[j];
  bool anyp = false;
  #pragma unroll
  for (int p = 0; p < PKP; ++p){
    float dx = nx - sKP[p*3+0], dy = ny - sKP[p*3+1], dz = nz - sKP[p*3+2];
    anyp |= (dx*dx + dy*dy + dz*dz < ext2);
  }
  unsigned long long act  = __ballot(anyp);
  unsigned long long good = __ballot(fs > 0.0f);
  unsigned int actH  = half ? (unsigned int)(act  >> 32) : (unsigned int)act;
  unsigned int goodH = half ? (unsigned int)(good >> 32) : (unsigned int)good;
  if (kk == 0){
    int cnt = __popc(goodH);
    invn[n] = 1.0f / (float)(cnt < 1 ? 1 : cnt);
    if (actH){
      int pos = atomicAdd(gcount, 1);
      list[pos] = n;
    }
  }
}

// --------------------------------------------------------------------------
__global__ __launch_bounds__(256) void k_conv_act(
    const float* __restrict__ pts, const int* __restrict__ nbr,
    const float* __restrict__ kp, const unsigned short* __restrict__ feat,
    const unsigned short* __restrict__ kpwT, const float* __restrict__ invn,
    const int* __restrict__ list, const int* __restrict__ gcount,
    unsigned short* __restrict__ kpfc, float ext2, float inv_ext){
  __shared__ float sW[PKP*128];
  __shared__ float sInfl[KNB*16];
  __shared__ unsigned int sPairP[KNB];
  __shared__ float sKP[45];
  __shared__ float sOut[128];
  __shared__ unsigned int sPmask, sPact;
  int tid = threadIdx.x;
  if (tid < 45) sKP[tid] = kp[tid];
  int cnt = *gcount;
  for (int it = blockIdx.x; it < cnt; it += gridDim.x){
    int n = list[it];
    if (tid == 0){ sPmask = 0u; sPact = 0u; }
    for (int i = tid; i < PKP*128; i += 256) sW[i] = 0.0f;
    __syncthreads();
    if (tid < KNB){
      int j = nbr[(size_t)n*KNB + tid];
      float nx = pts[j*3+0] - pts[n*3+0];
      float ny = pts[j*3+1] - pts[n*3+1];
      float nz = pts[j*3+2] - pts[n*3+2];
      unsigned int pm = 0u;
      #pragma unroll
      for (int p = 0; p < PKP; ++p){
        float dx = nx - sKP[p*3+0], dy = ny - sKP[p*3+1], dz = nz - sKP[p*3+2];
        float d2 = dx*dx + dy*dy + dz*dz;
        float infl = 0.0f;
        if (d2 < ext2){ infl = 1.0f - sqrtf(d2)*inv_ext; pm |= (1u << p); }
        sInfl[tid*16 + p] = infl;
      }
      sPairP[tid] = pm;
      if (pm){
        atomicOr(&sPact, 1u << tid);
        atomicOr(&sPmask, pm);
      }
    }
    __syncthreads();
    if (tid < 128){
      int c = tid;
      unsigned int m = sPact;
      while (m){
        int k = __ffs(m) - 1; m &= m - 1;
        int j = nbr[(size_t)n*KNB + k];
        float f = bf2f(feat[(size_t)j*128 + c]);
        unsigned int pp = sPairP[k];
        while (pp){
          int p = __ffs(pp) - 1; pp &= pp - 1;
          sW[p*128 + c] += sInfl[k*16 + p] * f;
        }
      }
    }
    __syncthreads();
    int d = tid & 127, h = tid >> 7;
    float acc = 0.0f;
    unsigned int pm = sPmask;
    while (pm){
      int p = __ffs(pm) - 1; pm &= pm - 1;
      const unsigned short* wp = kpwT + (size_t)d*1920 + p*128 + h*64;
      const float* wsrc = &sW[p*128 + h*64];
      #pragma unroll
      for (int c8 = 0; c8 < 8; ++c8){
        uint4 v = *(const uint4*)(wp + c8*8);
        unsigned int e[4] = {v.x, v.y, v.z, v.w};
        #pragma unroll
        for (int q = 0; q < 4; ++q){
          acc += wsrc[c8*8 + 2*q]     * bf2f((unsigned short)(e[q] & 0xffff));
          acc += wsrc[c8*8 + 2*q + 1] * bf2f((unsigned short)(e[q] >> 16));
        }
      }
    }
    if (h == 0) sOut[d] = acc;
    __syncthreads();
    if (h == 1) kpfc[(size_t)it*128 + d] = f2bf((sOut[d] + acc) * invn[n]);
    __syncthreads();
  }
}

// --------------------------------------------------------------------------
__global__ __launch_bounds__(256) void k_posmom1(
    const float* __restrict__ pts, const float* __restrict__ posW1,
    const float* __restrict__ stats, float* __restrict__ partials){
  __shared__ float sXm[64][65];
  int tid = threadIdx.x;
  int ia[9], ja[9];
  bool va[9];
  #pragma unroll
  for (int q = 0; q < 9; ++q){
    int idx = tid + q*256;
    va[q] = (idx < 2144);
    if (!va[q]){ ia[q] = 0; ja[q] = 0; continue; }
    if (idx < 64){ ia[q] = idx; ja[q] = -1; }
    else {
      int t = idx - 64; int i = 0;
      while (t >= 64 - i){ t -= 64 - i; ++i; }
      ia[q] = i; ja[q] = i + t;
    }
  }
  int c = tid & 63, rg = tid >> 6;
  float w0 = posW1[c], w1v = posW1[64+c], w2v = posW1[128+c];
  float sc1 = stats[256+c], sh1 = stats[320+c];
  int base = blockIdx.x*64;
  for (int r = rg; r < 64; r += 4){
    int row = base + r;
    sXm[r][c] = lrelu(sc1*(pts[row*3+0]*w0 + pts[row*3+1]*w1v
                         + pts[row*3+2]*w2v) + sh1);
  }
  __syncthreads();
  #pragma unroll
  for (int q = 0; q < 9; ++q){
    if (!va[q]) continue;
    float a = 0.0f;
    if (ja[q] < 0){
      for (int r = 0; r < 64; ++r) a += sXm[r][ia[q]];
    } else {
      for (int r = 0; r < 64; ++r) a += sXm[r][ia[q]]*sXm[r][ja[q]];
    }
    partials[(size_t)blockIdx.x*2144 + tid + q*256] = a;
  }
}

// --------------------------------------------------------------------------
__global__ __launch_bounds__(256) void k_posmom2(
    const float* __restrict__ partials, float* __restrict__ pm){
  int c = blockIdx.x*256 + threadIdx.x;
  if (c >= 2144) return;
  float a = 0.0f;
  for (int k = 0; k < 625; ++k) a += partials[(size_t)k*2144 + c];
  pm[c] = a;
}

// --------------------------------------------------------------------------
__global__ __launch_bounds__(256) void k_posbn2a(
    const float* __restrict__ pm, const float* __restrict__ posW2,
    float* __restrict__ U){
  __shared__ float sRow[64];
  int k = blockIdx.x;
  int tid = threadIdx.x;
  if (tid < 64){
    int i = k < tid ? k : tid, j = k < tid ? tid : k;
    int tri = i*64 - (i*(i-1))/2 + (j - i);
    sRow[tid] = pm[64 + tri];
  }
  __syncthreads();
  float a = 0.0f;
  for (int j = 0; j < 64; ++j) a += sRow[j]*posW2[j*256 + tid];
  U[k*256 + tid] = a;
}

// --------------------------------------------------------------------------
__global__ __launch_bounds__(256) void k_posbn2b(
    const float* __restrict__ pm, const float* __restrict__ U,
    const float* __restrict__ posW2, const float* __restrict__ b2,
    const float* __restrict__ g2, const float* __restrict__ bb2,
    float* __restrict__ stats){
  int c = threadIdx.x;
  float mlin = 0.0f, quad = 0.0f;
  for (int k = 0; k < 64; ++k){
    float wkc = posW2[k*256 + c];
    mlin += wkc * pm[k];
    quad += wkc * U[k*256 + c];
  }
  mlin *= INV_N; quad *= INV_N;
  float b = b2[c];
  float mean = mlin + b;
  float var = quad + 2.0f*b*mlin + b*b - mean*mean;
  float sc = g2[c]*rsqrtf(var + BNEPS);
  stats[384+c] = sc;
  stats[640+c] = bb2[c] - mean*sc + sc*b;
}

// --------------------------------------------------------------------------
// ufused v2 (proven 47us): cf-chunked accumulators, batched B-frag loads.
// --------------------------------------------------------------------------
__global__ __launch_bounds__(256) void k_ufused(
    const float* __restrict__ pts, const float* __restrict__ posW1,
    const float* __restrict__ stats, const unsigned short* __restrict__ posw2B,
    const unsigned short* __restrict__ uw1B, const float* __restrict__ ub_eff,
    unsigned short* __restrict__ u1, float* __restrict__ st2048){
  __shared__ __align__(16) unsigned short sX[4096];    // 8KB: X tile / epi staging
  __shared__ __align__(16) unsigned short sY[16384];   // 32KB: Y tile
  __shared__ float sC[512];
  __shared__ float sSum[128], sSq[128];
  int tid = threadIdx.x;
  int row0 = blockIdx.x*64;
  int w = tid >> 6, l = tid & 63;
  for (int i = tid; i < 512; i += 256) sC[i] = stats[384 + i];
  if (tid < 128){ sSum[tid] = 0.0f; sSq[tid] = 0.0f; }
  {
    int c = tid & 63, rg = tid >> 6;
    float w0 = posW1[c], w1v = posW1[64+c], w2v = posW1[128+c];
    float sc1 = stats[256+c], sh1 = stats[320+c];
    for (int r = rg; r < 64; r += 4){
      int row = row0 + r;
      float f = lrelu(sc1*(pts[row*3+0]*w0 + pts[row*3+1]*w1v
                         + pts[row*3+2]*w2v) + sh1);
      *(unsigned short*)((char*)sX + ((r*128 + c*2) ^ ((r&7)<<4))) = f2bf(f);
    }
  }
  __syncthreads();
  int rowA = w*16 + (l & 15);
  bf16x8 af0 = *(const bf16x8*)((const char*)sX +
               ((rowA*128 + ((l>>4)*8)*2) ^ ((rowA&7)<<4)));
  bf16x8 af1 = *(const bf16x8*)((const char*)sX +
               ((rowA*128 + (32+(l>>4)*8)*2) ^ ((rowA&7)<<4)));
  #pragma unroll
  for (int c4 = 0; c4 < 4; ++c4){
    bf16x8 b0[4], b1[4];
    #pragma unroll
    for (int j = 0; j < 4; ++j){
      int cf = c4*4 + j;
      b0[j] = *(const bf16x8*)(posw2B + (size_t)(cf*2+0)*512 + l*8);
      b1[j] = *(const bf16x8*)(posw2B + (size_t)(cf*2+1)*512 + l*8);
    }
    f32x4 acc[4] = {};
    #pragma unroll
    for (int j = 0; j < 4; ++j){
      acc[j] = __builtin_amdgcn_mfma_f32_16x16x32_bf16(af0, b0[j], acc[j], 0,0,0);
      acc[j] = __builtin_amdgcn_mfma_f32_16x16x32_bf16(af1, b1[j], acc[j], 0,0,0);
    }
    #pragma unroll
    for (int j = 0; j < 4; ++j){
      int col = (c4*4+j)*16 + (l & 15);
      float sc = sC[col], sh = sC[256+col];
      #pragma unroll
      for (int r = 0; r < 4; ++r){
        int row = w*16 + (l >> 4)*4 + r;
        float y = lrelu(sc*acc[j][r] + sh);
        *(unsigned short*)((char*)sY + ((row*512 + col*2) ^ ((row&7)<<4))) = f2bf(y);
      }
    }
  }
  __syncthreads();
  #pragma unroll
  for (int c4 = 0; c4 < 2; ++c4){
    f32x4 acc[4] = {};
    #pragma unroll
    for (int m = 0; m < 8; ++m){
      int ka = m*32 + (l >> 4)*8;
      bf16x8 af = *(const bf16x8*)((const char*)sY +
                  ((rowA*512 + ka*2) ^ ((rowA&7)<<4)));
      bf16x8 bb[4];
      #pragma unroll
      for (int j = 0; j < 4; ++j)
        bb[j] = *(const bf16x8*)(uw1B + (size_t)((c4*4+j)*8+m)*512 + l*8);
      #pragma unroll
      for (int j = 0; j < 4; ++j)
        acc[j] = __builtin_amdgcn_mfma_f32_16x16x32_bf16(af, bb[j], acc[j], 0,0,0);
    }
    #pragma unroll
    for (int j = 0; j < 4; ++j){
      int colh = j*16 + (l & 15);
      int col  = c4*64 + colh;
      float bj = ub_eff[col];
      float cs = 0.0f, cq = 0.0f;
      #pragma unroll
      for (int r = 0; r < 4; ++r){
        int row = w*16 + (l >> 4)*4 + r;
        float v = acc[j][r] + bj;
        *(unsigned short*)((char*)sX + ((row*128 + colh*2) ^ ((row&7)<<4))) = f2bf(v);
        cs += v; cq += v*v;
      }
      atomicAdd(&sSum[col], cs);
      atomicAdd(&sSq[col],  cq);
    }
    __syncthreads();
    #pragma unroll
    for (int ps = 0; ps < 2; ++ps){
      int idx = ps*256 + tid;
      int row = idx >> 3, g = idx & 7;
      uint4 v = *(const uint4*)((const char*)sX + ((row*128 + g*16) ^ ((row&7)<<4)));
      *(uint4*)(u1 + (size_t)(row0+row)*128 + c4*64 + g*8) = v;
    }
    __syncthreads();
  }
  if (tid < 128){
    atomicAdd(&st2048[tid],     sSum[tid]);
    atomicAdd(&st2048[128+tid], sSq[tid]);
  }
}

// --------------------------------------------------------------------------
__global__ __launch_bounds__(256) void k_rowgemm(
    const unsigned short* __restrict__ X,
    const float* __restrict__ st, const float* __restrict__ g,
    const float* __restrict__ bb, int K, int norm,
    const unsigned short* __restrict__ Wt, const float* __restrict__ bias,
    int NOUT, unsigned short* __restrict__ Y, float* __restrict__ statsOut,
    const int* __restrict__ list, const int* __restrict__ gcount){
  __shared__ float xs[256];
  __shared__ float sSc[256], sSh[256];
  int tid = threadIdx.x;
  if (norm && tid < K){
    float s = st[tid], q = st[K+tid];
    float mean = s*INV_N, var = q*INV_N - mean*mean;
    float sc = g[tid]*rsqrtf(var+BNEPS);
    sSc[tid] = sc; sSh[tid] = bb[tid] - mean*sc;
  }
  __syncthreads();
  int cnt = *gcount;
  float rs = 0.0f, rq = 0.0f;
  for (int it = blockIdx.x; it < cnt; it += gridDim.x){
    if (tid < K){
      float xv = bf2f(X[(size_t)it*K + tid]);
      if (norm) xv = lrelu(xv*sSc[tid] + sSh[tid]);
      xs[tid] = xv;
    }
    __syncthreads();
    if (tid < NOUT){
      float acc = bias[tid];
      const unsigned short* wp = Wt + (size_t)tid*K;
      for (int k8 = 0; k8 < K; k8 += 8){
        uint4 v = *(const uint4*)(wp + k8);
        unsigned int e[4] = {v.x, v.y, v.z, v.w};
        #pragma unroll
        for (int q = 0; q < 4; ++q){
          acc += xs[k8+2*q]   * bf2f((unsigned short)(e[q] & 0xffff));
          acc += xs[k8+2*q+1] * bf2f((unsigned short)(e[q] >> 16));
        }
      }
      Y[(size_t)it*NOUT + tid] = f2bf(acc);
      rs += acc; rq += acc*acc;
    }
    __syncthreads();
  }
  if (tid < NOUT && rs != 0.0f){
    atomicAdd(&statsOut[tid],      rs);
    atomicAdd(&statsOut[NOUT+tid], rq);
  }
}

// --------------------------------------------------------------------------
__global__ __launch_bounds__(256) void k_const1(
    const float* __restrict__ b1, const float* __restrict__ g1,
    const float* __restrict__ bb1, const unsigned short* __restrict__ aggw2T,
    const float* __restrict__ b2, float* __restrict__ st896,
    float* __restrict__ v2, const int* __restrict__ gcount){
  __shared__ float sX[256];
  int tid = threadIdx.x;
  float fN = (float)(NPTS - *gcount);
  float s = b1[tid];
  st896[tid]     += fN*s;
  st896[256+tid] += fN*s*s;
  float su = st896[tid], sq = st896[256+tid];
  float mean = su*INV_N, var = sq*INV_N - mean*mean;
  float sc = g1[tid]*rsqrtf(var+BNEPS);
  sX[tid] = lrelu(s*sc + bb1[tid] - mean*sc);
  __syncthreads();
  float acc = b2[tid];
  const unsigned short* wp = aggw2T + (size_t)tid*256;
  for (int k8 = 0; k8 < 256; k8 += 8){
    uint4 v = *(const uint4*)(wp + k8);
    unsigned int e[4] = {v.x, v.y, v.z, v.w};
    #pragma unroll
    for (int q = 0; q < 4; ++q){
      acc += sX[k8+2*q]   * bf2f((unsigned short)(e[q] & 0xffff));
      acc += sX[k8+2*q+1] * bf2f((unsigned short)(e[q] >> 16));
    }
  }
  v2[tid] = acc;
}

// --------------------------------------------------------------------------
__global__ __launch_bounds__(256) void k_const2(
    const float* __restrict__ v2, const float* __restrict__ g2,
    const float* __restrict__ bb2, const unsigned short* __restrict__ keepw1T,
    const float* __restrict__ kb1, const unsigned short* __restrict__ uw1T,
    const float* __restrict__ ub1, float* __restrict__ st1408,
    float* __restrict__ v3, float* __restrict__ ub_eff,
    const int* __restrict__ gcount){
  __shared__ float sX[256];
  int tid = threadIdx.x;
  float fN = (float)(NPTS - *gcount);
  float s = v2[tid];
  st1408[tid]     += fN*s;
  st1408[256+tid] += fN*s*s;
  float su = st1408[tid], sq = st1408[256+tid];
  float mean = su*INV_N, var = sq*INV_N - mean*mean;
  float sc = g2[tid]*rsqrtf(var+BNEPS);
  sX[tid] = lrelu(s*sc + bb2[tid] - mean*sc);
  __syncthreads();
  if (tid < 64){
    float acc = kb1[tid];
    const unsigned short* wp = keepw1T + (size_t)tid*256;
    for (int k8 = 0; k8 < 256; k8 += 8){
      uint4 v = *(const uint4*)(wp + k8);
      unsigned int e[4] = {v.x, v.y, v.z, v.w};
      #pragma unroll
      for (int q = 0; q < 4; ++q){
        acc += sX[k8+2*q]   * bf2f((unsigned short)(e[q] & 0xffff));
        acc += sX[k8+2*q+1] * bf2f((unsigned short)(e[q] >> 16));
      }
    }
    v3[tid] = acc;
  } else if (tid < 192){
    int c = tid - 64;
    float acc = ub1[c];
    const unsigned short* wp = uw1T + (size_t)c*512 + 256;
    for (int k8 = 0; k8 < 256; k8 += 8){
      uint4 v = *(const uint4*)(wp + k8);
      unsigned int e[4] = {v.x, v.y, v.z, v.w};
      #pragma unroll
      for (int q = 0; q < 4; ++q){
        acc += sX[k8+2*q]   * bf2f((unsigned short)(e[q] & 0xffff));
        acc += sX[k8+2*q+1] * bf2f((unsigned short)(e[q] >> 16));
      }
    }
    ub_eff[c] = acc;
  }
}

// --------------------------------------------------------------------------
__global__ __launch_bounds__(64) void k_const3(
    const float* __restrict__ v3, const float* __restrict__ g3,
    const float* __restrict__ bb3, const float* __restrict__ kw2,
    const float* __restrict__ kb2, float* __restrict__ st1920,
    float* __restrict__ s3out, const int* __restrict__ gcount){
  int tid = threadIdx.x;
  float fN = (float)(NPTS - *gcount);
  float s = v3[tid];
  st1920[tid]    += fN*s;
  st1920[64+tid] += fN*s*s;
  float su = st1920[tid], sq = st1920[64+tid];
  float mean = su*INV_N, var = sq*INV_N - mean*mean;
  float sc = g3[tid]*rsqrtf(var+BNEPS);
  float h = lrelu(s*sc + bb3[tid] - mean*sc) * kw2[tid];
  #pragma unroll
  for (int o = 32; o; o >>= 1) h += __shfl_down(h, o, 64);
  if (tid == 0) s3out[0] = 1.0f/(1.0f + expf(-(h + kb2[0])));
}

// --------------------------------------------------------------------------
__global__ __launch_bounds__(256) void k_udelta_keep(
    const unsigned short* __restrict__ a2c, const float* __restrict__ st1408,
    const float* __restrict__ g2, const float* __restrict__ bb2,
    const unsigned short* __restrict__ uw1T, const float* __restrict__ ub1,
    const float* __restrict__ ub_eff, unsigned short* __restrict__ u1,
    float* __restrict__ st2048,
    const unsigned short* __restrict__ k1c, const float* __restrict__ st1920,
    const float* __restrict__ g3, const float* __restrict__ b3,
    const float* __restrict__ kw2, const float* __restrict__ kb2,
    float* __restrict__ out,
    const int* __restrict__ list, const int* __restrict__ gcount){
  __shared__ float sX[256];
  __shared__ float sSc[256], sSh[256];
  int tid = threadIdx.x;
  int cnt = *gcount;
  if (blockIdx.x < 128){
    {
      float su = st1408[tid], sq = st1408[256+tid];
      float mean = su*INV_N, var = sq*INV_N - mean*mean;
      float sc = g2[tid]*rsqrtf(var+BNEPS);
      sSc[tid] = sc; sSh[tid] = bb2[tid] - mean*sc;
    }
    __syncthreads();
    for (int it = blockIdx.x; it < cnt; it += 128){
      int n = list[it];
      sX[tid] = lrelu(bf2f(a2c[(size_t)it*256 + tid])*sSc[tid] + sSh[tid]);
      __syncthreads();
      if (tid < 128){
        float acc = ub1[tid] - ub_eff[tid];
        const unsigned short* wp = uw1T + (size_t)tid*512 + 256;
        for (int k8 = 0; k8 < 256; k8 += 8){
          uint4 v = *(const uint4*)(wp + k8);
          unsigned int e[4] = {v.x, v.y, v.z, v.w};
          #pragma unroll
          for (int q = 0; q < 4; ++q){
            acc += sX[k8+2*q]   * bf2f((unsigned short)(e[q] & 0xffff));
            acc += sX[k8+2*q+1] * bf2f((unsigned short)(e[q] >> 16));
          }
        }
        float old = bf2f(u1[(size_t)n*128 + tid]);
        float neu = old + acc;
        u1[(size_t)n*128 + tid] = f2bf(neu);
        atomicAdd(&st2048[tid],     neu - old);
        atomicAdd(&st2048[128+tid], neu*neu - old*old);
      }
      __syncthreads();
    }
  } else {
    int lane = tid & 63;
    int wv = (blockIdx.x - 128)*4 + (tid >> 6);
    float su = st1920[lane], sq = st1920[64+lane];
    float mean = su*INV_N, var = sq*INV_N - mean*mean;
    float sc = g3[lane]*rsqrtf(var+BNEPS);
    float sh = b3[lane] - mean*sc;
    float w2v = kw2[lane];
    for (int it = wv; it < cnt; it += 128){
      float h = lrelu(bf2f(k1c[(size_t)it*64 + lane])*sc + sh) * w2v;
      #pragma unroll
      for (int o = 32; o; o >>= 1) h += __shfl_down(h, o, 64);
      if (lane == 0) out[list[it]] = 1.0f/(1.0f + expf(-(h + kb2[0])));
    }
  }
}

// --------------------------------------------------------------------------
__global__ __launch_bounds__(256) void k_uhead_out(
    const unsigned short* __restrict__ u1, const float* __restrict__ st2048,
    const float* __restrict__ g, const float* __restrict__ b,
    const float* __restrict__ w2, const float* __restrict__ b2,
    const int* __restrict__ nbr, const float* __restrict__ s3p,
    float* __restrict__ out){
  __shared__ float sSc[128], sSh[128], sW2[128];
  int tid = threadIdx.x;
  if (blockIdx.x >= 2500){
    int i = (blockIdx.x - 2500)*256 + tid;     // < 320000
    if (i < NPTS) out[i] = s3p[0];
    int4 v = ((const int4*)nbr)[i];
    ((float4*)(out + 2*NPTS))[i] =
        make_float4((float)v.x,(float)v.y,(float)v.z,(float)v.w);
    return;
  }
  if (tid < 128){
    float su = st2048[tid], sq = st2048[128+tid];
    float mean = su*INV_N, var = sq*INV_N - mean*mean;
    float sc = g[tid]*rsqrtf(var+BNEPS);
    sSc[tid] = sc; sSh[tid] = b[tid] - mean*sc;
    sW2[tid] = w2[tid];
  }
  __syncthreads();
  int lane = tid & 63, w = tid >> 6;
  for (int n = blockIdx.x*4 + w; n < NPTS; n += 10000){
    unsigned int v = *(const unsigned int*)(u1 + (size_t)n*128 + lane*2);
    int c0 = lane*2, c1 = c0 + 1;
    float h = lrelu(bf2f((unsigned short)(v & 0xffff))*sSc[c0] + sSh[c0])*sW2[c0]
            + lrelu(bf2f((unsigned short)(v >> 16))*sSc[c1] + sSh[c1])*sW2[c1];
    #pragma unroll
    for (int o = 32; o; o >>= 1) h += __shfl_down(h, o, 64);
    if (lane == 0) out[NPTS + n] = 1.0f/(1.0f + expf(-(h + b2[0])));
  }
}

// --------------------------------------------------------------------------
extern "C" void kernel_launch(void* const* d_in, const int* in_sizes, int n_in,
                              void* d_out, int out_size, void* d_ws, size_t ws_size,
                              hipStream_t stream) {
  const float* pts    = (const float*)d_in[0];
  const float* cov    = (const float*)d_in[1];
  const int*   nbr    = (const int*)  d_in[2];
  const float* pre_w  = (const float*)d_in[3];
  const float* pre_b  = (const float*)d_in[4];
  const float* pre_g  = (const float*)d_in[5];
  const float* pre_bb = (const float*)d_in[6];
  const float* kp     = (const float*)d_in[7];
  const float* kpw    = (const float*)d_in[8];
  const float* pos_w1 = (const float*)d_in[9];
  const float* pos_b1 = (const float*)d_in[10];
  const float* pos_g1 = (const float*)d_in[11];
  const float* pos_bb1= (const float*)d_in[12];
  const float* pos_w2 = (const float*)d_in[13];
  const float* pos_b2 = (const float*)d_in[14];
  const float* pos_g2 = (const float*)d_in[15];
  const float* pos_bb2= (const float*)d_in[16];
  const float* agg_w1 = (const float*)d_in[17];
  const float* agg_b1 = (const float*)d_in[18];
  const float* agg_g1 = (const float*)d_in[19];
  const float* agg_bb1= (const float*)d_in[20];
  const float* agg_w2 = (const float*)d_in[21];
  const float* agg_b2 = (const float*)d_in[22];
  const float* agg_g2 = (const float*)d_in[23];
  const float* agg_bb2= (const float*)d_in[24];
  const float* keep_w1= (const float*)d_in[25];
  const float* keep_b1= (const float*)d_in[26];
  const float* keep_g = (const float*)d_in[27];
  const float* keep_bb= (const float*)d_in[28];
  const float* keep_w2= (const float*)d_in[29];
  const float* keep_b2= (const float*)d_in[30];
  const float* uniq_w1= (const float*)d_in[31];
  const float* uniq_b1= (const float*)d_in[32];
  const float* uniq_g = (const float*)d_in[33];
  const float* uniq_bb= (const float*)d_in[34];
  const float* uniq_w2= (const float*)d_in[35];
  const float* uniq_b2= (const float*)d_in[36];

  float* out = (float*)d_out;

  // ---- ws layout ----
  char* wsb = (char*)d_ws;
  size_t off = 0;
  float* stats = (float*)(wsb + off); off += 8192*4;
  int*   gcount = (int*)(stats + 2304);
  float* s3     = stats + 2305;
  float* mom    = stats + 2320;
  float* v2     = stats + 2384;
  float* v3     = stats + 2640;
  float* ub_eff = stats + 2704;
  float* pm     = stats + 2832;              // 2144 floats (X moments)
  float* U      = (float*)(wsb + off); off += 16384*4;
  float* partials = (float*)(wsb + off); off += (size_t)625*2144*4;  // 5.36MB
  unsigned short* wT = (unsigned short*)(wsb + off); off += (size_t)442368*2;
  unsigned short* kpwT   = wT;
  unsigned short* aggw1T = wT + 262144;
  unsigned short* aggw2T = wT + 294912;
  unsigned short* keepw1T= wT + 360448;
  unsigned short* uniqw1T= wT + 376832;
  unsigned short* posw2B = (unsigned short*)(wsb + off); off += (size_t)16384*2;
  unsigned short* uw1B   = (unsigned short*)(wsb + off); off += (size_t)32768*2;
  float* fsum = (float*)(wsb + off); off += (size_t)NPTS*4;
  float* invn = (float*)(wsb + off); off += (size_t)NPTS*4;
  int*   list = (int*)  (wsb + off); off += (size_t)NPTS*4;
  unsigned short* feat = (unsigned short*)(wsb + off); off += (size_t)NPTS*128*2;
  unsigned short* kpfc = (unsigned short*)(wsb + off); off += (size_t)NPTS*128*2;
  unsigned short* a1c  = (unsigned short*)(wsb + off); off += (size_t)NPTS*256*2;
  unsigned short* a2c  = (unsigned short*)(wsb + off); off += (size_t)NPTS*256*2;
  unsigned short* k1c  = (unsigned short*)(wsb + off); off += (size_t)NPTS*64*2;
  unsigned short* u1   = (unsigned short*)(wsb + off); off += (size_t)NPTS*128*2;

  const double kpe = 1.0 / (cbrt(15.0) - 1.0) * 1.5;   // KP_EXTENT
  const float inv_ext = (float)(1.0 / kpe);
  const float ext2 = (float)(kpe * kpe);

  hipMemsetAsync(stats, 0, 2832*sizeof(float), stream);

  // prep: transposes + frag-pack + input moments
  k_prep<<<2080, 256, 0, stream>>>(kpw, pos_w2, agg_w1, agg_w2, keep_w1,
                                   uniq_w1, wT, posw2B, uw1B, cov, pts, mom);
  k_bnsetup<<<1, 256, 0, stream>>>(pre_w, pre_b, pre_g, pre_bb,
                                   pos_w1, pos_b1, pos_g1, pos_bb1, stats);
  k_feat<<<2500, 256, 0, stream>>>(cov, pre_w, stats, feat, fsum);
  k_scan<<<5000, 256, 0, stream>>>(pts, nbr, kp, fsum, invn, list, gcount, ext2);
  k_conv_act<<<1024, 256, 0, stream>>>(pts, nbr, kp, feat, kpwT, invn,
                                       list, gcount, kpfc, ext2, inv_ext);

  // pos-branch closed-form bn2 (two-stage deterministic moments)
  k_posmom1<<<625, 256, 0, stream>>>(pts, pos_w1, stats, partials);
  k_posmom2<<<9, 256, 0, stream>>>(partials, pm);
  k_posbn2a<<<64, 256, 0, stream>>>(pm, pos_w2, U);
  k_posbn2b<<<1, 256, 0, stream>>>(pm, U, pos_w2, pos_b2, pos_g2, pos_bb2, stats);

  // sparse agg chain
  k_rowgemm<<<256, 256, 0, stream>>>(kpfc, nullptr, nullptr, nullptr, 128, 0,
                                     aggw1T, agg_b1, 256, a1c, stats + 896,
                                     list, gcount);
  k_const1<<<1, 256, 0, stream>>>(agg_b1, agg_g1, agg_bb1, aggw2T, agg_b2,
                                  stats + 896, v2, gcount);
  k_rowgemm<<<256, 256, 0, stream>>>(a1c, stats + 896, agg_g1, agg_bb1, 256, 1,
                                     aggw2T, agg_b2, 256, a2c, stats + 1408,
                                     list, gcount);
  k_const2<<<1, 256, 0, stream>>>(v2, agg_g2, agg_bb2, keepw1T, keep_b1,
                                  uniqw1T, uniq_b1, stats + 1408, v3, ub_eff,
                                  gcount);
  k_rowgemm<<<256, 256, 0, stream>>>(a2c, stats + 1408, agg_g2, agg_bb2, 256, 1,
                                     keepw1T, keep_b1, 64, k1c, stats + 1920,
                                     list, gcount);
  k_const3<<<1, 64, 0, stream>>>(v3, keep_g, keep_bb, keep_w2, keep_b2,
                                 stats + 1920, s3, gcount);

  // uniq: fused pts->X->p2->bn2->u1; then active delta + keepact
  k_ufused<<<625, 256, 0, stream>>>(pts, pos_w1, stats, posw2B, uw1B,
                                    ub_eff, u1, stats + 2048);
  k_udelta_keep<<<160, 256, 0, stream>>>(a2c, stats + 1408, agg_g2, agg_bb2,
                                         uniqw1T, uniq_b1, ub_eff, u1,
                                         stats + 2048, k1c, stats + 1920,
                                         keep_g, keep_bb, keep_w2, keep_b2,
                                         out, list, gcount);
  // uhead + match-fill + idx passthrough
  k_uhead_out<<<3750, 256, 0, stream>>>(u1, stats + 2048, uniq_g, uniq_bb,
                                        uniq_w2, uniq_b2, nbr, s3, out);
}

// Round 20
// 258.356 us; speedup vs baseline: 1.1965x; 1.1555x over previous
//
#include <hip/hip_runtime.h>
#include <math.h>

// ---------------------------------------------------------------------------
// BimodalCompressor (round 20)
// r19 -> r20: k_posmom2 (46.5us, 9 blocks, 0.3% occupancy, 625 serial strided
// loads/thread) split into 2-level tree: k_posmom2a (grid 9x25, 25 chunks per
// block, coalesced) + k_posmom2b (grid 9, 25 iters). Deterministic fixed
// order. All else identical to r19 (locked r17 config).
// ---------------------------------------------------------------------------

#define NPTS 40000
#define KNB  32
#define PKP  15
#define SLOPE 0.01f
#define BNEPS 1e-5f
#define INV_N (1.0f/40000.0f)

typedef __attribute__((ext_vector_type(8))) short bf16x8;
typedef __attribute__((ext_vector_type(4))) float f32x4;

__device__ __forceinline__ float lrelu(float x){ return x >= 0.0f ? x : SLOPE*x; }
__device__ __forceinline__ unsigned short f2bf(float f){
  unsigned int b = __float_as_uint(f);
  b += 0x7fffu + ((b>>16)&1u);
  return (unsigned short)(b>>16);
}
__device__ __forceinline__ float bf2f(unsigned short u){
  return __uint_as_float(((unsigned int)u)<<16);
}

// stats layout: see r13 (unchanged)

// --------------------------------------------------------------------------
__global__ __launch_bounds__(256) void k_prep(
    const float* __restrict__ kpw,  const float* __restrict__ pw2,
    const float* __restrict__ aw1,  const float* __restrict__ aw2,
    const float* __restrict__ kw1,  const float* __restrict__ uw1,
    unsigned short* __restrict__ wT,
    unsigned short* __restrict__ posw2B, unsigned short* __restrict__ uw1B,
    const float* __restrict__ cov, const float* __restrict__ pts,
    float* __restrict__ mom){
  __shared__ float sM[63];
  int bid = blockIdx.x, tid = threadIdx.x;
  if (bid < 1728){
    int i = bid*256 + tid;     // < 442368
    const float* src; int K, N, off, li;
    if      (i < 245760){ src=kpw; K=1920; N=128; off=0;      li=i; }
    else if (i < 262144){ src=pw2; K=64;   N=256; off=245760; li=i-245760; }
    else if (i < 294912){ src=aw1; K=128;  N=256; off=262144; li=i-262144; }
    else if (i < 360448){ src=aw2; K=256;  N=256; off=294912; li=i-294912; }
    else if (i < 376832){ src=kw1; K=256;  N=64;  off=360448; li=i-360448; }
    else                { src=uw1; K=512;  N=128; off=376832; li=i-376832; }
    int k = li / N, n = li - k*N;
    wT[(size_t)off + (size_t)n*K + k] = f2bf(src[li]);
  } else if (bid < 1920){
    int i2 = (bid-1728)*256 + tid;     // < 49152
    if (i2 < 16384){
      int f = i2 >> 9, l = (i2 >> 3) & 63, j = i2 & 7;
      int cf = f >> 1, m = f & 1;
      int k = m*32 + (l>>4)*8 + j;
      int col = cf*16 + (l & 15);
      posw2B[i2] = f2bf(pw2[k*256 + col]);
    } else {
      int i3 = i2 - 16384;              // < 32768
      int f = i3 >> 9, l = (i3 >> 3) & 63, j = i3 & 7;
      int cf = f >> 3, m = f & 7;
      int k = m*32 + (l>>4)*8 + j;
      int c = cf*16 + (l & 15);
      uw1B[i3] = f2bf(uw1[k*128 + c]);
    }
  } else {
    // moments: one row per thread
    int lane = tid & 63;
    int row = (bid-1920)*256 + tid;     // < 40960
    if (tid < 63) sM[tid] = 0.0f;
    __syncthreads();
    float c9[9] = {0,0,0,0,0,0,0,0,0};
    float p3[3] = {0,0,0};
    if (row < NPTS){
      #pragma unroll
      for (int i = 0; i < 9; ++i) c9[i] = cov[row*9+i];
      #pragma unroll
      for (int i = 0; i < 3; ++i) p3[i] = pts[row*3+i];
    }
    float vals[63];
    int q = 0;
    #pragma unroll
    for (int i = 0; i < 9; ++i) vals[q++] = c9[i];
    #pragma unroll
    for (int i = 0; i < 9; ++i)
      #pragma unroll
      for (int j = i; j < 9; ++j) vals[q++] = c9[i]*c9[j];
    #pragma unroll
    for (int i = 0; i < 3; ++i) vals[q++] = p3[i];
    #pragma unroll
    for (int i = 0; i < 3; ++i)
      #pragma unroll
      for (int j = i; j < 3; ++j) vals[q++] = p3[i]*p3[j];
    #pragma unroll
    for (int qq = 0; qq < 63; ++qq){
      float v = vals[qq];
      #pragma unroll
      for (int o = 32; o; o >>= 1) v += __shfl_down(v, o, 64);
      if (lane == 0) atomicAdd(&sM[qq], v);
    }
    __syncthreads();
    if (tid < 63) atomicAdd(&mom[tid], sM[tid]);
  }
}

// --------------------------------------------------------------------------
__global__ __launch_bounds__(256) void k_bnsetup(
    const float* __restrict__ preW, const float* __restrict__ preB,
    const float* __restrict__ preG, const float* __restrict__ preBB,
    const float* __restrict__ posW1, const float* __restrict__ posB1,
    const float* __restrict__ posG1, const float* __restrict__ posBB1,
    float* __restrict__ stats){
  int tid = threadIdx.x;
  const float* mom = stats + 2320;
  if (tid < 128){
    int c = tid;
    float wv[9];
    #pragma unroll
    for (int i = 0; i < 9; ++i) wv[i] = preW[i*128+c];
    float b = preB[c];
    float mw = 0.0f;
    #pragma unroll
    for (int i = 0; i < 9; ++i) mw += wv[i]*mom[i];
    mw *= INV_N;
    float quad = 0.0f;
    for (int i = 0; i < 9; ++i)
      for (int j = 0; j < 9; ++j){
        int ii = i < j ? i : j, jj = i < j ? j : i;
        quad += wv[i]*wv[j]*mom[9 + ii*9 - (ii*(ii-1))/2 + (jj-ii)];
      }
    quad *= INV_N;
    float mean = mw + b;
    float var = quad + 2.0f*b*mw + b*b - mean*mean;
    float sc = preG[c]*rsqrtf(var+BNEPS);
    stats[c]     = sc;
    stats[128+c] = preBB[c] - mean*sc + sc*b;
  } else if (tid < 192){
    int c = tid - 128;
    float w0 = posW1[c], w1 = posW1[64+c], w2 = posW1[128+c];
    float b = posB1[c];
    const float* pm = mom + 54;
    const float* pM = mom + 57;
    float mw = (w0*pm[0] + w1*pm[1] + w2*pm[2])*INV_N;
    float quad = (w0*w0*pM[0] + w1*w1*pM[3] + w2*w2*pM[5]
               + 2.0f*(w0*w1*pM[1] + w0*w2*pM[2] + w1*w2*pM[4]))*INV_N;
    float mean = mw + b;
    float var = quad + 2.0f*b*mw + b*b - mean*mean;
    float sc = posG1[c]*rsqrtf(var+BNEPS);
    stats[256+c] = sc;
    stats[320+c] = posBB1[c] - mean*sc + sc*b;
  }
}

// --------------------------------------------------------------------------
__global__ __launch_bounds__(256) void k_feat(
    const float* __restrict__ cov, const float* __restrict__ preW,
    const float* __restrict__ stats, unsigned short* __restrict__ feat,
    float* __restrict__ fsum){
  int tid = threadIdx.x;
  int lane = tid & 63;
  int wv = (blockIdx.x*256 + tid) >> 6;
  int nw = gridDim.x*4;
  int c0 = lane, c1 = lane + 64;
  float w0[9], w1[9];
  #pragma unroll
  for (int i = 0; i < 9; ++i){ w0[i] = preW[i*128+c0]; w1[i] = preW[i*128+c1]; }
  float s0 = stats[c0], h0 = stats[128+c0];
  float s1 = stats[c1], h1 = stats[128+c1];
  for (int n = wv; n < NPTS; n += nw){
    float p0 = 0.0f, p1 = 0.0f;
    #pragma unroll
    for (int i = 0; i < 9; ++i){
      float x = cov[n*9+i];
      p0 += x*w0[i]; p1 += x*w1[i];
    }
    float f0 = lrelu(s0*p0 + h0);
    float f1 = lrelu(s1*p1 + h1);
    feat[(size_t)n*128 + c0] = f2bf(f0);
    feat[(size_t)n*128 + c1] = f2bf(f1);
    float t = f0 + f1;
    #pragma unroll
    for (int o = 32; o; o >>= 1) t += __shfl_down(t, o, 64);
    if (lane == 0) fsum[n] = t;
  }
}

// --------------------------------------------------------------------------
__global__ __launch_bounds__(256) void k_scan(
    const float* __restrict__ pts, const int* __restrict__ nbr,
    const float* __restrict__ kp, const float* __restrict__ fsum,
    float* __restrict__ invn, int* __restrict__ list,
    int* __restrict__ gcount, float ext2){
  __shared__ float sKP[45];
  if (threadIdx.x < 45) sKP[threadIdx.x] = kp[threadIdx.x];
  __syncthreads();
  int wv   = (blockIdx.x*256 + threadIdx.x) >> 6;
  int lane = threadIdx.x & 63;
  int half = lane >> 5;
  int kk   = lane & 31;
  int n    = wv*2 + half;
  float px = pts[n*3+0], py = pts[n*3+1], pz = pts[n*3+2];
  int j = nbr[(size_t)n*KNB + kk];
  float nx = pts[j*3+0] - px;
  float ny = pts[j*3+1] - py;
  float nz = pts[j*3+2] - pz;
  float fs = fsum[j];
  bool anyp = false;
  #pragma unroll
  for (int p = 0; p < PKP; ++p){
    float dx = nx - sKP[p*3+0], dy = ny - sKP[p*3+1], dz = nz - sKP[p*3+2];
    anyp |= (dx*dx + dy*dy + dz*dz < ext2);
  }
  unsigned long long act  = __ballot(anyp);
  unsigned long long good = __ballot(fs > 0.0f);
  unsigned int actH  = half ? (unsigned int)(act  >> 32) : (unsigned int)act;
  unsigned int goodH = half ? (unsigned int)(good >> 32) : (unsigned int)good;
  if (kk == 0){
    int cnt = __popc(goodH);
    invn[n] = 1.0f / (float)(cnt < 1 ? 1 : cnt);
    if (actH){
      int pos = atomicAdd(gcount, 1);
      list[pos] = n;
    }
  }
}

// --------------------------------------------------------------------------
__global__ __launch_bounds__(256) void k_conv_act(
    const float* __restrict__ pts, const int* __restrict__ nbr,
    const float* __restrict__ kp, const unsigned short* __restrict__ feat,
    const unsigned short* __restrict__ kpwT, const float* __restrict__ invn,
    const int* __restrict__ list, const int* __restrict__ gcount,
    unsigned short* __restrict__ kpfc, float ext2, float inv_ext){
  __shared__ float sW[PKP*128];
  __shared__ float sInfl[KNB*16];
  __shared__ unsigned int sPairP[KNB];
  __shared__ float sKP[45];
  __shared__ float sOut[128];
  __shared__ unsigned int sPmask, sPact;
  int tid = threadIdx.x;
  if (tid < 45) sKP[tid] = kp[tid];
  int cnt = *gcount;
  for (int it = blockIdx.x; it < cnt; it += gridDim.x){
    int n = list[it];
    if (tid == 0){ sPmask = 0u; sPact = 0u; }
    for (int i = tid; i < PKP*128; i += 256) sW[i] = 0.0f;
    __syncthreads();
    if (tid < KNB){
      int j = nbr[(size_t)n*KNB + tid];
      float nx = pts[j*3+0] - pts[n*3+0];
      float ny = pts[j*3+1] - pts[n*3+1];
      float nz = pts[j*3+2] - pts[n*3+2];
      unsigned int pm = 0u;
      #pragma unroll
      for (int p = 0; p < PKP; ++p){
        float dx = nx - sKP[p*3+0], dy = ny - sKP[p*3+1], dz = nz - sKP[p*3+2];
        float d2 = dx*dx + dy*dy + dz*dz;
        float infl = 0.0f;
        if (d2 < ext2){ infl = 1.0f - sqrtf(d2)*inv_ext; pm |= (1u << p); }
        sInfl[tid*16 + p] = infl;
      }
      sPairP[tid] = pm;
      if (pm){
        atomicOr(&sPact, 1u << tid);
        atomicOr(&sPmask, pm);
      }
    }
    __syncthreads();
    if (tid < 128){
      int c = tid;
      unsigned int m = sPact;
      while (m){
        int k = __ffs(m) - 1; m &= m - 1;
        int j = nbr[(size_t)n*KNB + k];
        float f = bf2f(feat[(size_t)j*128 + c]);
        unsigned int pp = sPairP[k];
        while (pp){
          int p = __ffs(pp) - 1; pp &= pp - 1;
          sW[p*128 + c] += sInfl[k*16 + p] * f;
        }
      }
    }
    __syncthreads();
    int d = tid & 127, h = tid >> 7;
    float acc = 0.0f;
    unsigned int pm = sPmask;
    while (pm){
      int p = __ffs(pm) - 1; pm &= pm - 1;
      const unsigned short* wp = kpwT + (size_t)d*1920 + p*128 + h*64;
      const float* wsrc = &sW[p*128 + h*64];
      #pragma unroll
      for (int c8 = 0; c8 < 8; ++c8){
        uint4 v = *(const uint4*)(wp + c8*8);
        unsigned int e[4] = {v.x, v.y, v.z, v.w};
        #pragma unroll
        for (int q = 0; q < 4; ++q){
          acc += wsrc[c8*8 + 2*q]     * bf2f((unsigned short)(e[q] & 0xffff));
          acc += wsrc[c8*8 + 2*q + 1] * bf2f((unsigned short)(e[q] >> 16));
        }
      }
    }
    if (h == 0) sOut[d] = acc;
    __syncthreads();
    if (h == 1) kpfc[(size_t)it*128 + d] = f2bf((sOut[d] + acc) * invn[n]);
    __syncthreads();
  }
}

// --------------------------------------------------------------------------
__global__ __launch_bounds__(256) void k_posmom1(
    const float* __restrict__ pts, const float* __restrict__ posW1,
    const float* __restrict__ stats, float* __restrict__ partials){
  __shared__ float sXm[64][65];
  int tid = threadIdx.x;
  int ia[9], ja[9];
  bool va[9];
  #pragma unroll
  for (int q = 0; q < 9; ++q){
    int idx = tid + q*256;
    va[q] = (idx < 2144);
    if (!va[q]){ ia[q] = 0; ja[q] = 0; continue; }
    if (idx < 64){ ia[q] = idx; ja[q] = -1; }
    else {
      int t = idx - 64; int i = 0;
      while (t >= 64 - i){ t -= 64 - i; ++i; }
      ia[q] = i; ja[q] = i + t;
    }
  }
  int c = tid & 63, rg = tid >> 6;
  float w0 = posW1[c], w1v = posW1[64+c], w2v = posW1[128+c];
  float sc1 = stats[256+c], sh1 = stats[320+c];
  int base = blockIdx.x*64;
  for (int r = rg; r < 64; r += 4){
    int row = base + r;
    sXm[r][c] = lrelu(sc1*(pts[row*3+0]*w0 + pts[row*3+1]*w1v
                         + pts[row*3+2]*w2v) + sh1);
  }
  __syncthreads();
  #pragma unroll
  for (int q = 0; q < 9; ++q){
    if (!va[q]) continue;
    float a = 0.0f;
    if (ja[q] < 0){
      for (int r = 0; r < 64; ++r) a += sXm[r][ia[q]];
    } else {
      for (int r = 0; r < 64; ++r) a += sXm[r][ia[q]]*sXm[r][ja[q]];
    }
    partials[(size_t)blockIdx.x*2144 + tid + q*256] = a;
  }
}

// --------------------------------------------------------------------------
// posmom2a: partials2[kb][c] = sum_{k=kb*25}^{kb*25+24} partials[k][c]
// grid (9, 25); coalesced column reads; deterministic fixed order.
// --------------------------------------------------------------------------
__global__ __launch_bounds__(256) void k_posmom2a(
    const float* __restrict__ partials, float* __restrict__ partials2){
  int c = blockIdx.x*256 + threadIdx.x;
  if (c >= 2144) return;
  int kb = blockIdx.y;
  float a = 0.0f;
  #pragma unroll 5
  for (int k = kb*25; k < kb*25 + 25; ++k)
    a += partials[(size_t)k*2144 + c];
  partials2[(size_t)kb*2144 + c] = a;
}

// --------------------------------------------------------------------------
// posmom2b: pm[c] = sum_{kb=0}^{24} partials2[kb][c]
// --------------------------------------------------------------------------
__global__ __launch_bounds__(256) void k_posmom2b(
    const float* __restrict__ partials2, float* __restrict__ pm){
  int c = blockIdx.x*256 + threadIdx.x;
  if (c >= 2144) return;
  float a = 0.0f;
  #pragma unroll 5
  for (int kb = 0; kb < 25; ++kb)
    a += partials2[(size_t)kb*2144 + c];
  pm[c] = a;
}

// --------------------------------------------------------------------------
__global__ __launch_bounds__(256) void k_posbn2a(
    const float* __restrict__ pm, const float* __restrict__ posW2,
    float* __restrict__ U){
  __shared__ float sRow[64];
  int k = blockIdx.x;
  int tid = threadIdx.x;
  if (tid < 64){
    int i = k < tid ? k : tid, j = k < tid ? tid : k;
    int tri = i*64 - (i*(i-1))/2 + (j - i);
    sRow[tid] = pm[64 + tri];
  }
  __syncthreads();
  float a = 0.0f;
  for (int j = 0; j < 64; ++j) a += sRow[j]*posW2[j*256 + tid];
  U[k*256 + tid] = a;
}

// --------------------------------------------------------------------------
__global__ __launch_bounds__(256) void k_posbn2b(
    const float* __restrict__ pm, const float* __restrict__ U,
    const float* __restrict__ posW2, const float* __restrict__ b2,
    const float* __restrict__ g2, const float* __restrict__ bb2,
    float* __restrict__ stats){
  int c = threadIdx.x;
  float mlin = 0.0f, quad = 0.0f;
  for (int k = 0; k < 64; ++k){
    float wkc = posW2[k*256 + c];
    mlin += wkc * pm[k];
    quad += wkc * U[k*256 + c];
  }
  mlin *= INV_N; quad *= INV_N;
  float b = b2[c];
  float mean = mlin + b;
  float var = quad + 2.0f*b*mlin + b*b - mean*mean;
  float sc = g2[c]*rsqrtf(var + BNEPS);
  stats[384+c] = sc;
  stats[640+c] = bb2[c] - mean*sc + sc*b;
}

// --------------------------------------------------------------------------
// ufused v2 (proven 47us): cf-chunked accumulators, batched B-frag loads.
// --------------------------------------------------------------------------
__global__ __launch_bounds__(256) void k_ufused(
    const float* __restrict__ pts, const float* __restrict__ posW1,
    const float* __restrict__ stats, const unsigned short* __restrict__ posw2B,
    const unsigned short* __restrict__ uw1B, const float* __restrict__ ub_eff,
    unsigned short* __restrict__ u1, float* __restrict__ st2048){
  __shared__ __align__(16) unsigned short sX[4096];    // 8KB: X tile / epi staging
  __shared__ __align__(16) unsigned short sY[16384];   // 32KB: Y tile
  __shared__ float sC[512];
  __shared__ float sSum[128], sSq[128];
  int tid = threadIdx.x;
  int row0 = blockIdx.x*64;
  int w = tid >> 6, l = tid & 63;
  for (int i = tid; i < 512; i += 256) sC[i] = stats[384 + i];
  if (tid < 128){ sSum[tid] = 0.0f; sSq[tid] = 0.0f; }
  {
    int c = tid & 63, rg = tid >> 6;
    float w0 = posW1[c], w1v = posW1[64+c], w2v = posW1[128+c];
    float sc1 = stats[256+c], sh1 = stats[320+c];
    for (int r = rg; r < 64; r += 4){
      int row = row0 + r;
      float f = lrelu(sc1*(pts[row*3+0]*w0 + pts[row*3+1]*w1v
                         + pts[row*3+2]*w2v) + sh1);
      *(unsigned short*)((char*)sX + ((r*128 + c*2) ^ ((r&7)<<4))) = f2bf(f);
    }
  }
  __syncthreads();
  int rowA = w*16 + (l & 15);
  bf16x8 af0 = *(const bf16x8*)((const char*)sX +
               ((rowA*128 + ((l>>4)*8)*2) ^ ((rowA&7)<<4)));
  bf16x8 af1 = *(const bf16x8*)((const char*)sX +
               ((rowA*128 + (32+(l>>4)*8)*2) ^ ((rowA&7)<<4)));
  #pragma unroll
  for (int c4 = 0; c4 < 4; ++c4){
    bf16x8 b0[4], b1[4];
    #pragma unroll
    for (int j = 0; j < 4; ++j){
      int cf = c4*4 + j;
      b0[j] = *(const bf16x8*)(posw2B + (size_t)(cf*2+0)*512 + l*8);
      b1[j] = *(const bf16x8*)(posw2B + (size_t)(cf*2+1)*512 + l*8);
    }
    f32x4 acc[4] = {};
    #pragma unroll
    for (int j = 0; j < 4; ++j){
      acc[j] = __builtin_amdgcn_mfma_f32_16x16x32_bf16(af0, b0[j], acc[j], 0,0,0);
      acc[j] = __builtin_amdgcn_mfma_f32_16x16x32_bf16(af1, b1[j], acc[j], 0,0,0);
    }
    #pragma unroll
    for (int j = 0; j < 4; ++j){
      int col = (c4*4+j)*16 + (l & 15);
      float sc = sC[col], sh = sC[256+col];
      #pragma unroll
      for (int r = 0; r < 4; ++r){
        int row = w*16 + (l >> 4)*4 + r;
        float y = lrelu(sc*acc[j][r] + sh);
        *(unsigned short*)((char*)sY + ((row*512 + col*2) ^ ((row&7)<<4))) = f2bf(y);
      }
    }
  }
  __syncthreads();
  #pragma unroll
  for (int c4 = 0; c4 < 2; ++c4){
    f32x4 acc[4] = {};
    #pragma unroll
    for (int m = 0; m < 8; ++m){
      int ka = m*32 + (l >> 4)*8;
      bf16x8 af = *(const bf16x8*)((const char*)sY +
                  ((rowA*512 + ka*2) ^ ((rowA&7)<<4)));
      bf16x8 bb[4];
      #pragma unroll
      for (int j = 0; j < 4; ++j)
        bb[j] = *(const bf16x8*)(uw1B + (size_t)((c4*4+j)*8+m)*512 + l*8);
      #pragma unroll
      for (int j = 0; j < 4; ++j)
        acc[j] = __builtin_amdgcn_mfma_f32_16x16x32_bf16(af, bb[j], acc[j], 0,0,0);
    }
    #pragma unroll
    for (int j = 0; j < 4; ++j){
      int colh = j*16 + (l & 15);
      int col  = c4*64 + colh;
      float bj = ub_eff[col];
      float cs = 0.0f, cq = 0.0f;
      #pragma unroll
      for (int r = 0; r < 4; ++r){
        int row = w*16 + (l >> 4)*4 + r;
        float v = acc[j][r] + bj;
        *(unsigned short*)((char*)sX + ((row*128 + colh*2) ^ ((row&7)<<4))) = f2bf(v);
        cs += v; cq += v*v;
      }
      atomicAdd(&sSum[col], cs);
      atomicAdd(&sSq[col],  cq);
    }
    __syncthreads();
    #pragma unroll
    for (int ps = 0; ps < 2; ++ps){
      int idx = ps*256 + tid;
      int row = idx >> 3, g = idx & 7;
      uint4 v = *(const uint4*)((const char*)sX + ((row*128 + g*16) ^ ((row&7)<<4)));
      *(uint4*)(u1 + (size_t)(row0+row)*128 + c4*64 + g*8) = v;
    }
    __syncthreads();
  }
  if (tid < 128){
    atomicAdd(&st2048[tid],     sSum[tid]);
    atomicAdd(&st2048[128+tid], sSq[tid]);
  }
}

// --------------------------------------------------------------------------
__global__ __launch_bounds__(256) void k_rowgemm(
    const unsigned short* __restrict__ X,
    const float* __restrict__ st, const float* __restrict__ g,
    const float* __restrict__ bb, int K, int norm,
    const unsigned short* __restrict__ Wt, const float* __restrict__ bias,
    int NOUT, unsigned short* __restrict__ Y, float* __restrict__ statsOut,
    const int* __restrict__ list, const int* __restrict__ gcount){
  __shared__ float xs[256];
  __shared__ float sSc[256], sSh[256];
  int tid = threadIdx.x;
  if (norm && tid < K){
    float s = st[tid], q = st[K+tid];
    float mean = s*INV_N, var = q*INV_N - mean*mean;
    float sc = g[tid]*rsqrtf(var+BNEPS);
    sSc[tid] = sc; sSh[tid] = bb[tid] - mean*sc;
  }
  __syncthreads();
  int cnt = *gcount;
  float rs = 0.0f, rq = 0.0f;
  for (int it = blockIdx.x; it < cnt; it += gridDim.x){
    if (tid < K){
      float xv = bf2f(X[(size_t)it*K + tid]);
      if (norm) xv = lrelu(xv*sSc[tid] + sSh[tid]);
      xs[tid] = xv;
    }
    __syncthreads();
    if (tid < NOUT){
      float acc = bias[tid];
      const unsigned short* wp = Wt + (size_t)tid*K;
      for (int k8 = 0; k8 < K; k8 += 8){
        uint4 v = *(const uint4*)(wp + k8);
        unsigned int e[4] = {v.x, v.y, v.z, v.w};
        #pragma unroll
        for (int q = 0; q < 4; ++q){
          acc += xs[k8+2*q]   * bf2f((unsigned short)(e[q] & 0xffff));
          acc += xs[k8+2*q+1] * bf2f((unsigned short)(e[q] >> 16));
        }
      }
      Y[(size_t)it*NOUT + tid] = f2bf(acc);
      rs += acc; rq += acc*acc;
    }
    __syncthreads();
  }
  if (tid < NOUT && rs != 0.0f){
    atomicAdd(&statsOut[tid],      rs);
    atomicAdd(&statsOut[NOUT+tid], rq);
  }
}

// --------------------------------------------------------------------------
__global__ __launch_bounds__(256) void k_const1(
    const float* __restrict__ b1, const float* __restrict__ g1,
    const float* __restrict__ bb1, const unsigned short* __restrict__ aggw2T,
    const float* __restrict__ b2, float* __restrict__ st896,
    float* __restrict__ v2, const int* __restrict__ gcount){
  __shared__ float sX[256];
  int tid = threadIdx.x;
  float fN = (float)(NPTS - *gcount);
  float s = b1[tid];
  st896[tid]     += fN*s;
  st896[256+tid] += fN*s*s;
  float su = st896[tid], sq = st896[256+tid];
  float mean = su*INV_N, var = sq*INV_N - mean*mean;
  float sc = g1[tid]*rsqrtf(var+BNEPS);
  sX[tid] = lrelu(s*sc + bb1[tid] - mean*sc);
  __syncthreads();
  float acc = b2[tid];
  const unsigned short* wp = aggw2T + (size_t)tid*256;
  for (int k8 = 0; k8 < 256; k8 += 8){
    uint4 v = *(const uint4*)(wp + k8);
    unsigned int e[4] = {v.x, v.y, v.z, v.w};
    #pragma unroll
    for (int q = 0; q < 4; ++q){
      acc += sX[k8+2*q]   * bf2f((unsigned short)(e[q] & 0xffff));
      acc += sX[k8+2*q+1] * bf2f((unsigned short)(e[q] >> 16));
    }
  }
  v2[tid] = acc;
}

// --------------------------------------------------------------------------
__global__ __launch_bounds__(256) void k_const2(
    const float* __restrict__ v2, const float* __restrict__ g2,
    const float* __restrict__ bb2, const unsigned short* __restrict__ keepw1T,
    const float* __restrict__ kb1, const unsigned short* __restrict__ uw1T,
    const float* __restrict__ ub1, float* __restrict__ st1408,
    float* __restrict__ v3, float* __restrict__ ub_eff,
    const int* __restrict__ gcount){
  __shared__ float sX[256];
  int tid = threadIdx.x;
  float fN = (float)(NPTS - *gcount);
  float s = v2[tid];
  st1408[tid]     += fN*s;
  st1408[256+tid] += fN*s*s;
  float su = st1408[tid], sq = st1408[256+tid];
  float mean = su*INV_N, var = sq*INV_N - mean*mean;
  float sc = g2[tid]*rsqrtf(var+BNEPS);
  sX[tid] = lrelu(s*sc + bb2[tid] - mean*sc);
  __syncthreads();
  if (tid < 64){
    float acc = kb1[tid];
    const unsigned short* wp = keepw1T + (size_t)tid*256;
    for (int k8 = 0; k8 < 256; k8 += 8){
      uint4 v = *(const uint4*)(wp + k8);
      unsigned int e[4] = {v.x, v.y, v.z, v.w};
      #pragma unroll
      for (int q = 0; q < 4; ++q){
        acc += sX[k8+2*q]   * bf2f((unsigned short)(e[q] & 0xffff));
        acc += sX[k8+2*q+1] * bf2f((unsigned short)(e[q] >> 16));
      }
    }
    v3[tid] = acc;
  } else if (tid < 192){
    int c = tid - 64;
    float acc = ub1[c];
    const unsigned short* wp = uw1T + (size_t)c*512 + 256;
    for (int k8 = 0; k8 < 256; k8 += 8){
      uint4 v = *(const uint4*)(wp + k8);
      unsigned int e[4] = {v.x, v.y, v.z, v.w};
      #pragma unroll
      for (int q = 0; q < 4; ++q){
        acc += sX[k8+2*q]   * bf2f((unsigned short)(e[q] & 0xffff));
        acc += sX[k8+2*q+1] * bf2f((unsigned short)(e[q] >> 16));
      }
    }
    ub_eff[c] = acc;
  }
}

// --------------------------------------------------------------------------
__global__ __launch_bounds__(64) void k_const3(
    const float* __restrict__ v3, const float* __restrict__ g3,
    const float* __restrict__ bb3, const float* __restrict__ kw2,
    const float* __restrict__ kb2, float* __restrict__ st1920,
    float* __restrict__ s3out, const int* __restrict__ gcount){
  int tid = threadIdx.x;
  float fN = (float)(NPTS - *gcount);
  float s = v3[tid];
  st1920[tid]    += fN*s;
  st1920[64+tid] += fN*s*s;
  float su = st1920[tid], sq = st1920[64+tid];
  float mean = su*INV_N, var = sq*INV_N - mean*mean;
  float sc = g3[tid]*rsqrtf(var+BNEPS);
  float h = lrelu(s*sc + bb3[tid] - mean*sc) * kw2[tid];
  #pragma unroll
  for (int o = 32; o; o >>= 1) h += __shfl_down(h, o, 64);
  if (tid == 0) s3out[0] = 1.0f/(1.0f + expf(-(h + kb2[0])));
}

// --------------------------------------------------------------------------
__global__ __launch_bounds__(256) void k_udelta_keep(
    const unsigned short* __restrict__ a2c, const float* __restrict__ st1408,
    const float* __restrict__ g2, const float* __restrict__ bb2,
    const unsigned short* __restrict__ uw1T, const float* __restrict__ ub1,
    const float* __restrict__ ub_eff, unsigned short* __restrict__ u1,
    float* __restrict__ st2048,
    const unsigned short* __restrict__ k1c, const float* __restrict__ st1920,
    const float* __restrict__ g3, const float* __restrict__ b3,
    const float* __restrict__ kw2, const float* __restrict__ kb2,
    float* __restrict__ out,
    const int* __restrict__ list, const int* __restrict__ gcount){
  __shared__ float sX[256];
  __shared__ float sSc[256], sSh[256];
  int tid = threadIdx.x;
  int cnt = *gcount;
  if (blockIdx.x < 128){
    {
      float su = st1408[tid], sq = st1408[256+tid];
      float mean = su*INV_N, var = sq*INV_N - mean*mean;
      float sc = g2[tid]*rsqrtf(var+BNEPS);
      sSc[tid] = sc; sSh[tid] = bb2[tid] - mean*sc;
    }
    __syncthreads();
    for (int it = blockIdx.x; it < cnt; it += 128){
      int n = list[it];
      sX[tid] = lrelu(bf2f(a2c[(size_t)it*256 + tid])*sSc[tid] + sSh[tid]);
      __syncthreads();
      if (tid < 128){
        float acc = ub1[tid] - ub_eff[tid];
        const unsigned short* wp = uw1T + (size_t)tid*512 + 256;
        for (int k8 = 0; k8 < 256; k8 += 8){
          uint4 v = *(const uint4*)(wp + k8);
          unsigned int e[4] = {v.x, v.y, v.z, v.w};
          #pragma unroll
          for (int q = 0; q < 4; ++q){
            acc += sX[k8+2*q]   * bf2f((unsigned short)(e[q] & 0xffff));
            acc += sX[k8+2*q+1] * bf2f((unsigned short)(e[q] >> 16));
          }
        }
        float old = bf2f(u1[(size_t)n*128 + tid]);
        float neu = old + acc;
        u1[(size_t)n*128 + tid] = f2bf(neu);
        atomicAdd(&st2048[tid],     neu - old);
        atomicAdd(&st2048[128+tid], neu*neu - old*old);
      }
      __syncthreads();
    }
  } else {
    int lane = tid & 63;
    int wv = (blockIdx.x - 128)*4 + (tid >> 6);
    float su = st1920[lane], sq = st1920[64+lane];
    float mean = su*INV_N, var = sq*INV_N - mean*mean;
    float sc = g3[lane]*rsqrtf(var+BNEPS);
    float sh = b3[lane] - mean*sc;
    float w2v = kw2[lane];
    for (int it = wv; it < cnt; it += 128){
      float h = lrelu(bf2f(k1c[(size_t)it*64 + lane])*sc + sh) * w2v;
      #pragma unroll
      for (int o = 32; o; o >>= 1) h += __shfl_down(h, o, 64);
      if (lane == 0) out[list[it]] = 1.0f/(1.0f + expf(-(h + kb2[0])));
    }
  }
}

// --------------------------------------------------------------------------
__global__ __launch_bounds__(256) void k_uhead_out(
    const unsigned short* __restrict__ u1, const float* __restrict__ st2048,
    const float* __restrict__ g, const float* __restrict__ b,
    const float* __restrict__ w2, const float* __restrict__ b2,
    const int* __restrict__ nbr, const float* __restrict__ s3p,
    float* __restrict__ out){
  __shared__ float sSc[128], sSh[128], sW2[128];
  int tid = threadIdx.x;
  if (blockIdx.x >= 2500){
    int i = (blockIdx.x - 2500)*256 + tid;     // < 320000
    if (i < NPTS) out[i] = s3p[0];
    int4 v = ((const int4*)nbr)[i];
    ((float4*)(out + 2*NPTS))[i] =
        make_float4((float)v.x,(float)v.y,(float)v.z,(float)v.w);
    return;
  }
  if (tid < 128){
    float su = st2048[tid], sq = st2048[128+tid];
    float mean = su*INV_N, var = sq*INV_N - mean*mean;
    float sc = g[tid]*rsqrtf(var+BNEPS);
    sSc[tid] = sc; sSh[tid] = b[tid] - mean*sc;
    sW2[tid] = w2[tid];
  }
  __syncthreads();
  int lane = tid & 63, w = tid >> 6;
  for (int n = blockIdx.x*4 + w; n < NPTS; n += 10000){
    unsigned int v = *(const unsigned int*)(u1 + (size_t)n*128 + lane*2);
    int c0 = lane*2, c1 = c0 + 1;
    float h = lrelu(bf2f((unsigned short)(v & 0xffff))*sSc[c0] + sSh[c0])*sW2[c0]
            + lrelu(bf2f((unsigned short)(v >> 16))*sSc[c1] + sSh[c1])*sW2[c1];
    #pragma unroll
    for (int o = 32; o; o >>= 1) h += __shfl_down(h, o, 64);
    if (lane == 0) out[NPTS + n] = 1.0f/(1.0f + expf(-(h + b2[0])));
  }
}

// --------------------------------------------------------------------------
extern "C" void kernel_launch(void* const* d_in, const int* in_sizes, int n_in,
                              void* d_out, int out_size, void* d_ws, size_t ws_size,
                              hipStream_t stream) {
  const float* pts    = (const float*)d_in[0];
  const float* cov    = (const float*)d_in[1];
  const int*   nbr    = (const int*)  d_in[2];
  const float* pre_w  = (const float*)d_in[3];
  const float* pre_b  = (const float*)d_in[4];
  const float* pre_g  = (const float*)d_in[5];
  const float* pre_bb = (const float*)d_in[6];
  const float* kp     = (const float*)d_in[7];
  const float* kpw    = (const float*)d_in[8];
  const float* pos_w1 = (const float*)d_in[9];
  const float* pos_b1 = (const float*)d_in[10];
  const float* pos_g1 = (const float*)d_in[11];
  const float* pos_bb1= (const float*)d_in[12];
  const float* pos_w2 = (const float*)d_in[13];
  const float* pos_b2 = (const float*)d_in[14];
  const float* pos_g2 = (const float*)d_in[15];
  const float* pos_bb2= (const float*)d_in[16];
  const float* agg_w1 = (const float*)d_in[17];
  const float* agg_b1 = (const float*)d_in[18];
  const float* agg_g1 = (const float*)d_in[19];
  const float* agg_bb1= (const float*)d_in[20];
  const float* agg_w2 = (const float*)d_in[21];
  const float* agg_b2 = (const float*)d_in[22];
  const float* agg_g2 = (const float*)d_in[23];
  const float* agg_bb2= (const float*)d_in[24];
  const float* keep_w1= (const float*)d_in[25];
  const float* keep_b1= (const float*)d_in[26];
  const float* keep_g = (const float*)d_in[27];
  const float* keep_bb= (const float*)d_in[28];
  const float* keep_w2= (const float*)d_in[29];
  const float* keep_b2= (const float*)d_in[30];
  const float* uniq_w1= (const float*)d_in[31];
  const float* uniq_b1= (const float*)d_in[32];
  const float* uniq_g = (const float*)d_in[33];
  const float* uniq_bb= (const float*)d_in[34];
  const float* uniq_w2= (const float*)d_in[35];
  const float* uniq_b2= (const float*)d_in[36];

  float* out = (float*)d_out;

  // ---- ws layout ----
  char* wsb = (char*)d_ws;
  size_t off = 0;
  float* stats = (float*)(wsb + off); off += 8192*4;
  int*   gcount = (int*)(stats + 2304);
  float* s3     = stats + 2305;
  float* mom    = stats + 2320;
  float* v2     = stats + 2384;
  float* v3     = stats + 2640;
  float* ub_eff = stats + 2704;
  float* pm     = stats + 2832;              // 2144 floats (X moments)
  float* U      = (float*)(wsb + off); off += 16384*4;
  float* partials  = (float*)(wsb + off); off += (size_t)625*2144*4; // 5.36MB
  float* partials2 = (float*)(wsb + off); off += (size_t)25*2144*4;  // 214KB
  unsigned short* wT = (unsigned short*)(wsb + off); off += (size_t)442368*2;
  unsigned short* kpwT   = wT;
  unsigned short* aggw1T = wT + 262144;
  unsigned short* aggw2T = wT + 294912;
  unsigned short* keepw1T= wT + 360448;
  unsigned short* uniqw1T= wT + 376832;
  unsigned short* posw2B = (unsigned short*)(wsb + off); off += (size_t)16384*2;
  unsigned short* uw1B   = (unsigned short*)(wsb + off); off += (size_t)32768*2;
  float* fsum = (float*)(wsb + off); off += (size_t)NPTS*4;
  float* invn = (float*)(wsb + off); off += (size_t)NPTS*4;
  int*   list = (int*)  (wsb + off); off += (size_t)NPTS*4;
  unsigned short* feat = (unsigned short*)(wsb + off); off += (size_t)NPTS*128*2;
  unsigned short* kpfc = (unsigned short*)(wsb + off); off += (size_t)NPTS*128*2;
  unsigned short* a1c  = (unsigned short*)(wsb + off); off += (size_t)NPTS*256*2;
  unsigned short* a2c  = (unsigned short*)(wsb + off); off += (size_t)NPTS*256*2;
  unsigned short* k1c  = (unsigned short*)(wsb + off); off += (size_t)NPTS*64*2;
  unsigned short* u1   = (unsigned short*)(wsb + off); off += (size_t)NPTS*128*2;

  const double kpe = 1.0 / (cbrt(15.0) - 1.0) * 1.5;   // KP_EXTENT
  const float inv_ext = (float)(1.0 / kpe);
  const float ext2 = (float)(kpe * kpe);

  hipMemsetAsync(stats, 0, 2832*sizeof(float), stream);

  // prep: transposes + frag-pack + input moments
  k_prep<<<2080, 256, 0, stream>>>(kpw, pos_w2, agg_w1, agg_w2, keep_w1,
                                   uniq_w1, wT, posw2B, uw1B, cov, pts, mom);
  k_bnsetup<<<1, 256, 0, stream>>>(pre_w, pre_b, pre_g, pre_bb,
                                   pos_w1, pos_b1, pos_g1, pos_bb1, stats);
  k_feat<<<2500, 256, 0, stream>>>(cov, pre_w, stats, feat, fsum);
  k_scan<<<5000, 256, 0, stream>>>(pts, nbr, kp, fsum, invn, list, gcount, ext2);
  k_conv_act<<<1024, 256, 0, stream>>>(pts, nbr, kp, feat, kpwT, invn,
                                       list, gcount, kpfc, ext2, inv_ext);

  // pos-branch closed-form bn2 (3-stage deterministic moments)
  k_posmom1<<<625, 256, 0, stream>>>(pts, pos_w1, stats, partials);
  k_posmom2a<<<dim3(9, 25), 256, 0, stream>>>(partials, partials2);
  k_posmom2b<<<9, 256, 0, stream>>>(partials2, pm);
  k_posbn2a<<<64, 256, 0, stream>>>(pm, pos_w2, U);
  k_posbn2b<<<1, 256, 0, stream>>>(pm, U, pos_w2, pos_b2, pos_g2, pos_bb2, stats);

  // sparse agg chain
  k_rowgemm<<<256, 256, 0, stream>>>(kpfc, nullptr, nullptr, nullptr, 128, 0,
                                     aggw1T, agg_b1, 256, a1c, stats + 896,
                                     list, gcount);
  k_const1<<<1, 256, 0, stream>>>(agg_b1, agg_g1, agg_bb1, aggw2T, agg_b2,
                                  stats + 896, v2, gcount);
  k_rowgemm<<<256, 256, 0, stream>>>(a1c, stats + 896, agg_g1, agg_bb1, 256, 1,
                                     aggw2T, agg_b2, 256, a2c, stats + 1408,
                                     list, gcount);
  k_const2<<<1, 256, 0, stream>>>(v2, agg_g2, agg_bb2, keepw1T, keep_b1,
                                  uniqw1T, uniq_b1, stats + 1408, v3, ub_eff,
                                  gcount);
  k_rowgemm<<<256, 256, 0, stream>>>(a2c, stats + 1408, agg_g2, agg_bb2, 256, 1,
                                     keepw1T, keep_b1, 64, k1c, stats + 1920,
                                     list, gcount);
  k_const3<<<1, 64, 0, stream>>>(v3, keep_g, keep_bb, keep_w2, keep_b2,
                                 stats + 1920, s3, gcount);

  // uniq: fused pts->X->p2->bn2->u1; then active delta + keepact
  k_ufused<<<625, 256, 0, stream>>>(pts, pos_w1, stats, posw2B, uw1B,
                                    ub_eff, u1, stats + 2048);
  k_udelta_keep<<<160, 256, 0, stream>>>(a2c, stats + 1408, agg_g2, agg_bb2,
                                         uniqw1T, uniq_b1, ub_eff, u1,
                                         stats + 2048, k1c, stats + 1920,
                                         keep_g, keep_bb, keep_w2, keep_b2,
                                         out, list, gcount);
  // uhead + match-fill + idx passthrough
  k_uhead_out<<<3750, 256, 0, stream>>>(u1, stats + 2048, uniq_g, uniq_bb,
                                        uniq_w2, uniq_b2, nbr, s3, out);
}

// Round 21
// 256.866 us; speedup vs baseline: 1.2035x; 1.0058x over previous
//
#include <hip/hip_runtime.h>
#include <math.h>

// ---------------------------------------------------------------------------
// BimodalCompressor (round 21)
// r20 -> r21: k_ufused MFMA1 two-deep B-frag software pipeline (ping-pong
// named register sets, static indexing; math order unchanged -> u1 identical).
// All else identical to r20 (258.4us, passed).
// ---------------------------------------------------------------------------

#define NPTS 40000
#define KNB  32
#define PKP  15
#define SLOPE 0.01f
#define BNEPS 1e-5f
#define INV_N (1.0f/40000.0f)

typedef __attribute__((ext_vector_type(8))) short bf16x8;
typedef __attribute__((ext_vector_type(4))) float f32x4;

__device__ __forceinline__ float lrelu(float x){ return x >= 0.0f ? x : SLOPE*x; }
__device__ __forceinline__ unsigned short f2bf(float f){
  unsigned int b = __float_as_uint(f);
  b += 0x7fffu + ((b>>16)&1u);
  return (unsigned short)(b>>16);
}
__device__ __forceinline__ float bf2f(unsigned short u){
  return __uint_as_float(((unsigned int)u)<<16);
}

// stats layout: see r13 (unchanged)

// --------------------------------------------------------------------------
__global__ __launch_bounds__(256) void k_prep(
    const float* __restrict__ kpw,  const float* __restrict__ pw2,
    const float* __restrict__ aw1,  const float* __restrict__ aw2,
    const float* __restrict__ kw1,  const float* __restrict__ uw1,
    unsigned short* __restrict__ wT,
    unsigned short* __restrict__ posw2B, unsigned short* __restrict__ uw1B,
    const float* __restrict__ cov, const float* __restrict__ pts,
    float* __restrict__ mom){
  __shared__ float sM[63];
  int bid = blockIdx.x, tid = threadIdx.x;
  if (bid < 1728){
    int i = bid*256 + tid;     // < 442368
    const float* src; int K, N, off, li;
    if      (i < 245760){ src=kpw; K=1920; N=128; off=0;      li=i; }
    else if (i < 262144){ src=pw2; K=64;   N=256; off=245760; li=i-245760; }
    else if (i < 294912){ src=aw1; K=128;  N=256; off=262144; li=i-262144; }
    else if (i < 360448){ src=aw2; K=256;  N=256; off=294912; li=i-294912; }
    else if (i < 376832){ src=kw1; K=256;  N=64;  off=360448; li=i-360448; }
    else                { src=uw1; K=512;  N=128; off=376832; li=i-376832; }
    int k = li / N, n = li - k*N;
    wT[(size_t)off + (size_t)n*K + k] = f2bf(src[li]);
  } else if (bid < 1920){
    int i2 = (bid-1728)*256 + tid;     // < 49152
    if (i2 < 16384){
      int f = i2 >> 9, l = (i2 >> 3) & 63, j = i2 & 7;
      int cf = f >> 1, m = f & 1;
      int k = m*32 + (l>>4)*8 + j;
      int col = cf*16 + (l & 15);
      posw2B[i2] = f2bf(pw2[k*256 + col]);
    } else {
      int i3 = i2 - 16384;              // < 32768
      int f = i3 >> 9, l = (i3 >> 3) & 63, j = i3 & 7;
      int cf = f >> 3, m = f & 7;
      int k = m*32 + (l>>4)*8 + j;
      int c = cf*16 + (l & 15);
      uw1B[i3] = f2bf(uw1[k*128 + c]);
    }
  } else {
    // moments: one row per thread
    int lane = tid & 63;
    int row = (bid-1920)*256 + tid;     // < 40960
    if (tid < 63) sM[tid] = 0.0f;
    __syncthreads();
    float c9[9] = {0,0,0,0,0,0,0,0,0};
    float p3[3] = {0,0,0};
    if (row < NPTS){
      #pragma unroll
      for (int i = 0; i < 9; ++i) c9[i] = cov[row*9+i];
      #pragma unroll
      for (int i = 0; i < 3; ++i) p3[i] = pts[row*3+i];
    }
    float vals[63];
    int q = 0;
    #pragma unroll
    for (int i = 0; i < 9; ++i) vals[q++] = c9[i];
    #pragma unroll
    for (int i = 0; i < 9; ++i)
      #pragma unroll
      for (int j = i; j < 9; ++j) vals[q++] = c9[i]*c9[j];
    #pragma unroll
    for (int i = 0; i < 3; ++i) vals[q++] = p3[i];
    #pragma unroll
    for (int i = 0; i < 3; ++i)
      #pragma unroll
      for (int j = i; j < 3; ++j) vals[q++] = p3[i]*p3[j];
    #pragma unroll
    for (int qq = 0; qq < 63; ++qq){
      float v = vals[qq];
      #pragma unroll
      for (int o = 32; o; o >>= 1) v += __shfl_down(v, o, 64);
      if (lane == 0) atomicAdd(&sM[qq], v);
    }
    __syncthreads();
    if (tid < 63) atomicAdd(&mom[tid], sM[tid]);
  }
}

// --------------------------------------------------------------------------
__global__ __launch_bounds__(256) void k_bnsetup(
    const float* __restrict__ preW, const float* __restrict__ preB,
    const float* __restrict__ preG, const float* __restrict__ preBB,
    const float* __restrict__ posW1, const float* __restrict__ posB1,
    const float* __restrict__ posG1, const float* __restrict__ posBB1,
    float* __restrict__ stats){
  int tid = threadIdx.x;
  const float* mom = stats + 2320;
  if (tid < 128){
    int c = tid;
    float wv[9];
    #pragma unroll
    for (int i = 0; i < 9; ++i) wv[i] = preW[i*128+c];
    float b = preB[c];
    float mw = 0.0f;
    #pragma unroll
    for (int i = 0; i < 9; ++i) mw += wv[i]*mom[i];
    mw *= INV_N;
    float quad = 0.0f;
    for (int i = 0; i < 9; ++i)
      for (int j = 0; j < 9; ++j){
        int ii = i < j ? i : j, jj = i < j ? j : i;
        quad += wv[i]*wv[j]*mom[9 + ii*9 - (ii*(ii-1))/2 + (jj-ii)];
      }
    quad *= INV_N;
    float mean = mw + b;
    float var = quad + 2.0f*b*mw + b*b - mean*mean;
    float sc = preG[c]*rsqrtf(var+BNEPS);
    stats[c]     = sc;
    stats[128+c] = preBB[c] - mean*sc + sc*b;
  } else if (tid < 192){
    int c = tid - 128;
    float w0 = posW1[c], w1 = posW1[64+c], w2 = posW1[128+c];
    float b = posB1[c];
    const float* pm = mom + 54;
    const float* pM = mom + 57;
    float mw = (w0*pm[0] + w1*pm[1] + w2*pm[2])*INV_N;
    float quad = (w0*w0*pM[0] + w1*w1*pM[3] + w2*w2*pM[5]
               + 2.0f*(w0*w1*pM[1] + w0*w2*pM[2] + w1*w2*pM[4]))*INV_N;
    float mean = mw + b;
    float var = quad + 2.0f*b*mw + b*b - mean*mean;
    float sc = posG1[c]*rsqrtf(var+BNEPS);
    stats[256+c] = sc;
    stats[320+c] = posBB1[c] - mean*sc + sc*b;
  }
}

// --------------------------------------------------------------------------
__global__ __launch_bounds__(256) void k_feat(
    const float* __restrict__ cov, const float* __restrict__ preW,
    const float* __restrict__ stats, unsigned short* __restrict__ feat,
    float* __restrict__ fsum){
  int tid = threadIdx.x;
  int lane = tid & 63;
  int wv = (blockIdx.x*256 + tid) >> 6;
  int nw = gridDim.x*4;
  int c0 = lane, c1 = lane + 64;
  float w0[9], w1[9];
  #pragma unroll
  for (int i = 0; i < 9; ++i){ w0[i] = preW[i*128+c0]; w1[i] = preW[i*128+c1]; }
  float s0 = stats[c0], h0 = stats[128+c0];
  float s1 = stats[c1], h1 = stats[128+c1];
  for (int n = wv; n < NPTS; n += nw){
    float p0 = 0.0f, p1 = 0.0f;
    #pragma unroll
    for (int i = 0; i < 9; ++i){
      float x = cov[n*9+i];
      p0 += x*w0[i]; p1 += x*w1[i];
    }
    float f0 = lrelu(s0*p0 + h0);
    float f1 = lrelu(s1*p1 + h1);
    feat[(size_t)n*128 + c0] = f2bf(f0);
    feat[(size_t)n*128 + c1] = f2bf(f1);
    float t = f0 + f1;
    #pragma unroll
    for (int o = 32; o; o >>= 1) t += __shfl_down(t, o, 64);
    if (lane == 0) fsum[n] = t;
  }
}

// --------------------------------------------------------------------------
__global__ __launch_bounds__(256) void k_scan(
    const float* __restrict__ pts, const int* __restrict__ nbr,
    const float* __restrict__ kp, const float* __restrict__ fsum,
    float* __restrict__ invn, int* __restrict__ list,
    int* __restrict__ gcount, float ext2){
  __shared__ float sKP[45];
  if (threadIdx.x < 45) sKP[threadIdx.x] = kp[threadIdx.x];
  __syncthreads();
  int wv   = (blockIdx.x*256 + threadIdx.x) >> 6;
  int lane = threadIdx.x & 63;
  int half = lane >> 5;
  int kk   = lane & 31;
  int n    = wv*2 + half;
  float px = pts[n*3+0], py = pts[n*3+1], pz = pts[n*3+2];
  int j = nbr[(size_t)n*KNB + kk];
  float nx = pts[j*3+0] - px;
  float ny = pts[j*3+1] - py;
  float nz = pts[j*3+2] - pz;
  float fs = fsum[j];
  bool anyp = false;
  #pragma unroll
  for (int p = 0; p < PKP; ++p){
    float dx = nx - sKP[p*3+0], dy = ny - sKP[p*3+1], dz = nz - sKP[p*3+2];
    anyp |= (dx*dx + dy*dy + dz*dz < ext2);
  }
  unsigned long long act  = __ballot(anyp);
  unsigned long long good = __ballot(fs > 0.0f);
  unsigned int actH  = half ? (unsigned int)(act  >> 32) : (unsigned int)act;
  unsigned int goodH = half ? (unsigned int)(good >> 32) : (unsigned int)good;
  if (kk == 0){
    int cnt = __popc(goodH);
    invn[n] = 1.0f / (float)(cnt < 1 ? 1 : cnt);
    if (actH){
      int pos = atomicAdd(gcount, 1);
      list[pos] = n;
    }
  }
}

// --------------------------------------------------------------------------
__global__ __launch_bounds__(256) void k_conv_act(
    const float* __restrict__ pts, const int* __restrict__ nbr,
    const float* __restrict__ kp, const unsigned short* __restrict__ feat,
    const unsigned short* __restrict__ kpwT, const float* __restrict__ invn,
    const int* __restrict__ list, const int* __restrict__ gcount,
    unsigned short* __restrict__ kpfc, float ext2, float inv_ext){
  __shared__ float sW[PKP*128];
  __shared__ float sInfl[KNB*16];
  __shared__ unsigned int sPairP[KNB];
  __shared__ float sKP[45];
  __shared__ float sOut[128];
  __shared__ unsigned int sPmask, sPact;
  int tid = threadIdx.x;
  if (tid < 45) sKP[tid] = kp[tid];
  int cnt = *gcount;
  for (int it = blockIdx.x; it < cnt; it += gridDim.x){
    int n = list[it];
    if (tid == 0){ sPmask = 0u; sPact = 0u; }
    for (int i = tid; i < PKP*128; i += 256) sW[i] = 0.0f;
    __syncthreads();
    if (tid < KNB){
      int j = nbr[(size_t)n*KNB + tid];
      float nx = pts[j*3+0] - pts[n*3+0];
      float ny = pts[j*3+1] - pts[n*3+1];
      float nz = pts[j*3+2] - pts[n*3+2];
      unsigned int pm = 0u;
      #pragma unroll
      for (int p = 0; p < PKP; ++p){
        float dx = nx - sKP[p*3+0], dy = ny - sKP[p*3+1], dz = nz - sKP[p*3+2];
        float d2 = dx*dx + dy*dy + dz*dz;
        float infl = 0.0f;
        if (d2 < ext2){ infl = 1.0f - sqrtf(d2)*inv_ext; pm |= (1u << p); }
        sInfl[tid*16 + p] = infl;
      }
      sPairP[tid] = pm;
      if (pm){
        atomicOr(&sPact, 1u << tid);
        atomicOr(&sPmask, pm);
      }
    }
    __syncthreads();
    if (tid < 128){
      int c = tid;
      unsigned int m = sPact;
      while (m){
        int k = __ffs(m) - 1; m &= m - 1;
        int j = nbr[(size_t)n*KNB + k];
        float f = bf2f(feat[(size_t)j*128 + c]);
        unsigned int pp = sPairP[k];
        while (pp){
          int p = __ffs(pp) - 1; pp &= pp - 1;
          sW[p*128 + c] += sInfl[k*16 + p] * f;
        }
      }
    }
    __syncthreads();
    int d = tid & 127, h = tid >> 7;
    float acc = 0.0f;
    unsigned int pm = sPmask;
    while (pm){
      int p = __ffs(pm) - 1; pm &= pm - 1;
      const unsigned short* wp = kpwT + (size_t)d*1920 + p*128 + h*64;
      const float* wsrc = &sW[p*128 + h*64];
      #pragma unroll
      for (int c8 = 0; c8 < 8; ++c8){
        uint4 v = *(const uint4*)(wp + c8*8);
        unsigned int e[4] = {v.x, v.y, v.z, v.w};
        #pragma unroll
        for (int q = 0; q < 4; ++q){
          acc += wsrc[c8*8 + 2*q]     * bf2f((unsigned short)(e[q] & 0xffff));
          acc += wsrc[c8*8 + 2*q + 1] * bf2f((unsigned short)(e[q] >> 16));
        }
      }
    }
    if (h == 0) sOut[d] = acc;
    __syncthreads();
    if (h == 1) kpfc[(size_t)it*128 + d] = f2bf((sOut[d] + acc) * invn[n]);
    __syncthreads();
  }
}

// --------------------------------------------------------------------------
__global__ __launch_bounds__(256) void k_posmom1(
    const float* __restrict__ pts, const float* __restrict__ posW1,
    const float* __restrict__ stats, float* __restrict__ partials){
  __shared__ float sXm[64][65];
  int tid = threadIdx.x;
  int ia[9], ja[9];
  bool va[9];
  #pragma unroll
  for (int q = 0; q < 9; ++q){
    int idx = tid + q*256;
    va[q] = (idx < 2144);
    if (!va[q]){ ia[q] = 0; ja[q] = 0; continue; }
    if (idx < 64){ ia[q] = idx; ja[q] = -1; }
    else {
      int t = idx - 64; int i = 0;
      while (t >= 64 - i){ t -= 64 - i; ++i; }
      ia[q] = i; ja[q] = i + t;
    }
  }
  int c = tid & 63, rg = tid >> 6;
  float w0 = posW1[c], w1v = posW1[64+c], w2v = posW1[128+c];
  float sc1 = stats[256+c], sh1 = stats[320+c];
  int base = blockIdx.x*64;
  for (int r = rg; r < 64; r += 4){
    int row = base + r;
    sXm[r][c] = lrelu(sc1*(pts[row*3+0]*w0 + pts[row*3+1]*w1v
                         + pts[row*3+2]*w2v) + sh1);
  }
  __syncthreads();
  #pragma unroll
  for (int q = 0; q < 9; ++q){
    if (!va[q]) continue;
    float a = 0.0f;
    if (ja[q] < 0){
      for (int r = 0; r < 64; ++r) a += sXm[r][ia[q]];
    } else {
      for (int r = 0; r < 64; ++r) a += sXm[r][ia[q]]*sXm[r][ja[q]];
    }
    partials[(size_t)blockIdx.x*2144 + tid + q*256] = a;
  }
}

// --------------------------------------------------------------------------
__global__ __launch_bounds__(256) void k_posmom2a(
    const float* __restrict__ partials, float* __restrict__ partials2){
  int c = blockIdx.x*256 + threadIdx.x;
  if (c >= 2144) return;
  int kb = blockIdx.y;
  float a = 0.0f;
  #pragma unroll 5
  for (int k = kb*25; k < kb*25 + 25; ++k)
    a += partials[(size_t)k*2144 + c];
  partials2[(size_t)kb*2144 + c] = a;
}

// --------------------------------------------------------------------------
__global__ __launch_bounds__(256) void k_posmom2b(
    const float* __restrict__ partials2, float* __restrict__ pm){
  int c = blockIdx.x*256 + threadIdx.x;
  if (c >= 2144) return;
  float a = 0.0f;
  #pragma unroll 5
  for (int kb = 0; kb < 25; ++kb)
    a += partials2[(size_t)kb*2144 + c];
  pm[c] = a;
}

// --------------------------------------------------------------------------
__global__ __launch_bounds__(256) void k_posbn2a(
    const float* __restrict__ pm, const float* __restrict__ posW2,
    float* __restrict__ U){
  __shared__ float sRow[64];
  int k = blockIdx.x;
  int tid = threadIdx.x;
  if (tid < 64){
    int i = k < tid ? k : tid, j = k < tid ? tid : k;
    int tri = i*64 - (i*(i-1))/2 + (j - i);
    sRow[tid] = pm[64 + tri];
  }
  __syncthreads();
  float a = 0.0f;
  for (int j = 0; j < 64; ++j) a += sRow[j]*posW2[j*256 + tid];
  U[k*256 + tid] = a;
}

// --------------------------------------------------------------------------
__global__ __launch_bounds__(256) void k_posbn2b(
    const float* __restrict__ pm, const float* __restrict__ U,
    const float* __restrict__ posW2, const float* __restrict__ b2,
    const float* __restrict__ g2, const float* __restrict__ bb2,
    float* __restrict__ stats){
  int c = threadIdx.x;
  float mlin = 0.0f, quad = 0.0f;
  for (int k = 0; k < 64; ++k){
    float wkc = posW2[k*256 + c];
    mlin += wkc * pm[k];
    quad += wkc * U[k*256 + c];
  }
  mlin *= INV_N; quad *= INV_N;
  float b = b2[c];
  float mean = mlin + b;
  float var = quad + 2.0f*b*mlin + b*b - mean*mean;
  float sc = g2[c]*rsqrtf(var + BNEPS);
  stats[384+c] = sc;
  stats[640+c] = bb2[c] - mean*sc + sc*b;
}

// --------------------------------------------------------------------------
// k_ufused helpers: B-frag loads + MFMA1 chunk compute (static indexing).
// --------------------------------------------------------------------------
__device__ __forceinline__ void uf_loadB1(
    const unsigned short* __restrict__ posw2B, int l, int c4,
    bf16x8 (&B0)[4], bf16x8 (&B1)[4]){
  #pragma unroll
  for (int j = 0; j < 4; ++j){
    int cf = c4*4 + j;
    B0[j] = *(const bf16x8*)(posw2B + (size_t)(cf*2+0)*512 + l*8);
    B1[j] = *(const bf16x8*)(posw2B + (size_t)(cf*2+1)*512 + l*8);
  }
}

__device__ __forceinline__ void uf_comp1(
    bf16x8 af0, bf16x8 af1, bf16x8 (&B0)[4], bf16x8 (&B1)[4],
    const float* __restrict__ sC, unsigned short* __restrict__ sY,
    int w, int l, int c4){
  f32x4 acc[4] = {};
  #pragma unroll
  for (int j = 0; j < 4; ++j){
    acc[j] = __builtin_amdgcn_mfma_f32_16x16x32_bf16(af0, B0[j], acc[j], 0,0,0);
    acc[j] = __builtin_amdgcn_mfma_f32_16x16x32_bf16(af1, B1[j], acc[j], 0,0,0);
  }
  #pragma unroll
  for (int j = 0; j < 4; ++j){
    int col = (c4*4+j)*16 + (l & 15);
    float sc = sC[320 - 320 + col];            // sC[col]
    float sh = sC[256 + col];
    #pragma unroll
    for (int r = 0; r < 4; ++r){
      int row = w*16 + (l >> 4)*4 + r;
      float y = lrelu(sc*acc[j][r] + sh);
      *(unsigned short*)((char*)sY + ((row*512 + col*2) ^ ((row&7)<<4))) = f2bf(y);
    }
  }
}

// --------------------------------------------------------------------------
// ufused v2p: v2 with MFMA1 two-deep B-frag prefetch (ping-pong sets).
// Math order identical to v2 -> u1 bit-identical.
// --------------------------------------------------------------------------
__global__ __launch_bounds__(256) void k_ufused(
    const float* __restrict__ pts, const float* __restrict__ posW1,
    const float* __restrict__ stats, const unsigned short* __restrict__ posw2B,
    const unsigned short* __restrict__ uw1B, const float* __restrict__ ub_eff,
    unsigned short* __restrict__ u1, float* __restrict__ st2048){
  __shared__ __align__(16) unsigned short sX[4096];    // 8KB: X tile / epi staging
  __shared__ __align__(16) unsigned short sY[16384];   // 32KB: Y tile
  __shared__ float sC[512];
  __shared__ float sSum[128], sSq[128];
  int tid = threadIdx.x;
  int row0 = blockIdx.x*64;
  int w = tid >> 6, l = tid & 63;
  for (int i = tid; i < 512; i += 256) sC[i] = stats[384 + i];
  if (tid < 128){ sSum[tid] = 0.0f; sSq[tid] = 0.0f; }
  {
    int c = tid & 63, rg = tid >> 6;
    float w0 = posW1[c], w1v = posW1[64+c], w2v = posW1[128+c];
    float sc1 = stats[256+c], sh1 = stats[320+c];
    for (int r = rg; r < 64; r += 4){
      int row = row0 + r;
      float f = lrelu(sc1*(pts[row*3+0]*w0 + pts[row*3+1]*w1v
                         + pts[row*3+2]*w2v) + sh1);
      *(unsigned short*)((char*)sX + ((r*128 + c*2) ^ ((r&7)<<4))) = f2bf(f);
    }
  }
  __syncthreads();
  int rowA = w*16 + (l & 15);
  bf16x8 af0 = *(const bf16x8*)((const char*)sX +
               ((rowA*128 + ((l>>4)*8)*2) ^ ((rowA&7)<<4)));
  bf16x8 af1 = *(const bf16x8*)((const char*)sX +
               ((rowA*128 + (32+(l>>4)*8)*2) ^ ((rowA&7)<<4)));
  // MFMA1: software-pipelined (two-deep), ping-pong register sets
  {
    bf16x8 pA0[4], pA1[4], pB0[4], pB1[4];
    uf_loadB1(posw2B, l, 0, pA0, pA1);
    uf_loadB1(posw2B, l, 1, pB0, pB1);
    uf_comp1(af0, af1, pA0, pA1, sC, sY, w, l, 0);
    uf_loadB1(posw2B, l, 2, pA0, pA1);
    uf_comp1(af0, af1, pB0, pB1, sC, sY, w, l, 1);
    uf_loadB1(posw2B, l, 3, pB0, pB1);
    uf_comp1(af0, af1, pA0, pA1, sC, sY, w, l, 2);
    uf_comp1(af0, af1, pB0, pB1, sC, sY, w, l, 3);
  }
  __syncthreads();
  #pragma unroll
  for (int c4 = 0; c4 < 2; ++c4){
    f32x4 acc[4] = {};
    #pragma unroll
    for (int m = 0; m < 8; ++m){
      int ka = m*32 + (l >> 4)*8;
      bf16x8 af = *(const bf16x8*)((const char*)sY +
                  ((rowA*512 + ka*2) ^ ((rowA&7)<<4)));
      bf16x8 bb[4];
      #pragma unroll
      for (int j = 0; j < 4; ++j)
        bb[j] = *(const bf16x8*)(uw1B + (size_t)((c4*4+j)*8+m)*512 + l*8);
      #pragma unroll
      for (int j = 0; j < 4; ++j)
        acc[j] = __builtin_amdgcn_mfma_f32_16x16x32_bf16(af, bb[j], acc[j], 0,0,0);
    }
    #pragma unroll
    for (int j = 0; j < 4; ++j){
      int colh = j*16 + (l & 15);
      int col  = c4*64 + colh;
      float bj = ub_eff[col];
      float cs = 0.0f, cq = 0.0f;
      #pragma unroll
      for (int r = 0; r < 4; ++r){
        int row = w*16 + (l >> 4)*4 + r;
        float v = acc[j][r] + bj;
        *(unsigned short*)((char*)sX + ((row*128 + colh*2) ^ ((row&7)<<4))) = f2bf(v);
        cs += v; cq += v*v;
      }
      atomicAdd(&sSum[col], cs);
      atomicAdd(&sSq[col],  cq);
    }
    __syncthreads();
    #pragma unroll
    for (int ps = 0; ps < 2; ++ps){
      int idx = ps*256 + tid;
      int row = idx >> 3, g = idx & 7;
      uint4 v = *(const uint4*)((const char*)sX + ((row*128 + g*16) ^ ((row&7)<<4)));
      *(uint4*)(u1 + (size_t)(row0+row)*128 + c4*64 + g*8) = v;
    }
    __syncthreads();
  }
  if (tid < 128){
    atomicAdd(&st2048[tid],     sSum[tid]);
    atomicAdd(&st2048[128+tid], sSq[tid]);
  }
}

// --------------------------------------------------------------------------
__global__ __launch_bounds__(256) void k_rowgemm(
    const unsigned short* __restrict__ X,
    const float* __restrict__ st, const float* __restrict__ g,
    const float* __restrict__ bb, int K, int norm,
    const unsigned short* __restrict__ Wt, const float* __restrict__ bias,
    int NOUT, unsigned short* __restrict__ Y, float* __restrict__ statsOut,
    const int* __restrict__ list, const int* __restrict__ gcount){
  __shared__ float xs[256];
  __shared__ float sSc[256], sSh[256];
  int tid = threadIdx.x;
  if (norm && tid < K){
    float s = st[tid], q = st[K+tid];
    float mean = s*INV_N, var = q*INV_N - mean*mean;
    float sc = g[tid]*rsqrtf(var+BNEPS);
    sSc[tid] = sc; sSh[tid] = bb[tid] - mean*sc;
  }
  __syncthreads();
  int cnt = *gcount;
  float rs = 0.0f, rq = 0.0f;
  for (int it = blockIdx.x; it < cnt; it += gridDim.x){
    if (tid < K){
      float xv = bf2f(X[(size_t)it*K + tid]);
      if (norm) xv = lrelu(xv*sSc[tid] + sSh[tid]);
      xs[tid] = xv;
    }
    __syncthreads();
    if (tid < NOUT){
      float acc = bias[tid];
      const unsigned short* wp = Wt + (size_t)tid*K;
      for (int k8 = 0; k8 < K; k8 += 8){
        uint4 v = *(const uint4*)(wp + k8);
        unsigned int e[4] = {v.x, v.y, v.z, v.w};
        #pragma unroll
        for (int q = 0; q < 4; ++q){
          acc += xs[k8+2*q]   * bf2f((unsigned short)(e[q] & 0xffff));
          acc += xs[k8+2*q+1] * bf2f((unsigned short)(e[q] >> 16));
        }
      }
      Y[(size_t)it*NOUT + tid] = f2bf(acc);
      rs += acc; rq += acc*acc;
    }
    __syncthreads();
  }
  if (tid < NOUT && rs != 0.0f){
    atomicAdd(&statsOut[tid],      rs);
    atomicAdd(&statsOut[NOUT+tid], rq);
  }
}

// --------------------------------------------------------------------------
__global__ __launch_bounds__(256) void k_const1(
    const float* __restrict__ b1, const float* __restrict__ g1,
    const float* __restrict__ bb1, const unsigned short* __restrict__ aggw2T,
    const float* __restrict__ b2, float* __restrict__ st896,
    float* __restrict__ v2, const int* __restrict__ gcount){
  __shared__ float sX[256];
  int tid = threadIdx.x;
  float fN = (float)(NPTS - *gcount);
  float s = b1[tid];
  st896[tid]     += fN*s;
  st896[256+tid] += fN*s*s;
  float su = st896[tid], sq = st896[256+tid];
  float mean = su*INV_N, var = sq*INV_N - mean*mean;
  float sc = g1[tid]*rsqrtf(var+BNEPS);
  sX[tid] = lrelu(s*sc + bb1[tid] - mean*sc);
  __syncthreads();
  float acc = b2[tid];
  const unsigned short* wp = aggw2T + (size_t)tid*256;
  for (int k8 = 0; k8 < 256; k8 += 8){
    uint4 v = *(const uint4*)(wp + k8);
    unsigned int e[4] = {v.x, v.y, v.z, v.w};
    #pragma unroll
    for (int q = 0; q < 4; ++q){
      acc += sX[k8+2*q]   * bf2f((unsigned short)(e[q] & 0xffff));
      acc += sX[k8+2*q+1] * bf2f((unsigned short)(e[q] >> 16));
    }
  }
  v2[tid] = acc;
}

// --------------------------------------------------------------------------
__global__ __launch_bounds__(256) void k_const2(
    const float* __restrict__ v2, const float* __restrict__ g2,
    const float* __restrict__ bb2, const unsigned short* __restrict__ keepw1T,
    const float* __restrict__ kb1, const unsigned short* __restrict__ uw1T,
    const float* __restrict__ ub1, float* __restrict__ st1408,
    float* __restrict__ v3, float* __restrict__ ub_eff,
    const int* __restrict__ gcount){
  __shared__ float sX[256];
  int tid = threadIdx.x;
  float fN = (float)(NPTS - *gcount);
  float s = v2[tid];
  st1408[tid]     += fN*s;
  st1408[256+tid] += fN*s*s;
  float su = st1408[tid], sq = st1408[256+tid];
  float mean = su*INV_N, var = sq*INV_N - mean*mean;
  float sc = g2[tid]*rsqrtf(var+BNEPS);
  sX[tid] = lrelu(s*sc + bb2[tid] - mean*sc);
  __syncthreads();
  if (tid < 64){
    float acc = kb1[tid];
    const unsigned short* wp = keepw1T + (size_t)tid*256;
    for (int k8 = 0; k8 < 256; k8 += 8){
      uint4 v = *(const uint4*)(wp + k8);
      unsigned int e[4] = {v.x, v.y, v.z, v.w};
      #pragma unroll
      for (int q = 0; q < 4; ++q){
        acc += sX[k8+2*q]   * bf2f((unsigned short)(e[q] & 0xffff));
        acc += sX[k8+2*q+1] * bf2f((unsigned short)(e[q] >> 16));
      }
    }
    v3[tid] = acc;
  } else if (tid < 192){
    int c = tid - 64;
    float acc = ub1[c];
    const unsigned short* wp = uw1T + (size_t)c*512 + 256;
    for (int k8 = 0; k8 < 256; k8 += 8){
      uint4 v = *(const uint4*)(wp + k8);
      unsigned int e[4] = {v.x, v.y, v.z, v.w};
      #pragma unroll
      for (int q = 0; q < 4; ++q){
        acc += sX[k8+2*q]   * bf2f((unsigned short)(e[q] & 0xffff));
        acc += sX[k8+2*q+1] * bf2f((unsigned short)(e[q] >> 16));
      }
    }
    ub_eff[c] = acc;
  }
}

// --------------------------------------------------------------------------
__global__ __launch_bounds__(64) void k_const3(
    const float* __restrict__ v3, const float* __restrict__ g3,
    const float* __restrict__ bb3, const float* __restrict__ kw2,
    const float* __restrict__ kb2, float* __restrict__ st1920,
    float* __restrict__ s3out, const int* __restrict__ gcount){
  int tid = threadIdx.x;
  float fN = (float)(NPTS - *gcount);
  float s = v3[tid];
  st1920[tid]    += fN*s;
  st1920[64+tid] += fN*s*s;
  float su = st1920[tid], sq = st1920[64+tid];
  float mean = su*INV_N, var = sq*INV_N - mean*mean;
  float sc = g3[tid]*rsqrtf(var+BNEPS);
  float h = lrelu(s*sc + bb3[tid] - mean*sc) * kw2[tid];
  #pragma unroll
  for (int o = 32; o; o >>= 1) h += __shfl_down(h, o, 64);
  if (tid == 0) s3out[0] = 1.0f/(1.0f + expf(-(h + kb2[0])));
}

// --------------------------------------------------------------------------
__global__ __launch_bounds__(256) void k_udelta_keep(
    const unsigned short* __restrict__ a2c, const float* __restrict__ st1408,
    const float* __restrict__ g2, const float* __restrict__ bb2,
    const unsigned short* __restrict__ uw1T, const float* __restrict__ ub1,
    const float* __restrict__ ub_eff, unsigned short* __restrict__ u1,
    float* __restrict__ st2048,
    const unsigned short* __restrict__ k1c, const float* __restrict__ st1920,
    const float* __restrict__ g3, const float* __restrict__ b3,
    const float* __restrict__ kw2, const float* __restrict__ kb2,
    float* __restrict__ out,
    const int* __restrict__ list, const int* __restrict__ gcount){
  __shared__ float sX[256];
  __shared__ float sSc[256], sSh[256];
  int tid = threadIdx.x;
  int cnt = *gcount;
  if (blockIdx.x < 128){
    {
      float su = st1408[tid], sq = st1408[256+tid];
      float mean = su*INV_N, var = sq*INV_N - mean*mean;
      float sc = g2[tid]*rsqrtf(var+BNEPS);
      sSc[tid] = sc; sSh[tid] = bb2[tid] - mean*sc;
    }
    __syncthreads();
    for (int it = blockIdx.x; it < cnt; it += 128){
      int n = list[it];
      sX[tid] = lrelu(bf2f(a2c[(size_t)it*256 + tid])*sSc[tid] + sSh[tid]);
      __syncthreads();
      if (tid < 128){
        float acc = ub1[tid] - ub_eff[tid];
        const unsigned short* wp = uw1T + (size_t)tid*512 + 256;
        for (int k8 = 0; k8 < 256; k8 += 8){
          uint4 v = *(const uint4*)(wp + k8);
          unsigned int e[4] = {v.x, v.y, v.z, v.w};
          #pragma unroll
          for (int q = 0; q < 4; ++q){
            acc += sX[k8+2*q]   * bf2f((unsigned short)(e[q] & 0xffff));
            acc += sX[k8+2*q+1] * bf2f((unsigned short)(e[q] >> 16));
          }
        }
        float old = bf2f(u1[(size_t)n*128 + tid]);
        float neu = old + acc;
        u1[(size_t)n*128 + tid] = f2bf(neu);
        atomicAdd(&st2048[tid],     neu - old);
        atomicAdd(&st2048[128+tid], neu*neu - old*old);
      }
      __syncthreads();
    }
  } else {
    int lane = tid & 63;
    int wv = (blockIdx.x - 128)*4 + (tid >> 6);
    float su = st1920[lane], sq = st1920[64+lane];
    float mean = su*INV_N, var = sq*INV_N - mean*mean;
    float sc = g3[lane]*rsqrtf(var+BNEPS);
    float sh = b3[lane] - mean*sc;
    float w2v = kw2[lane];
    for (int it = wv; it < cnt; it += 128){
      float h = lrelu(bf2f(k1c[(size_t)it*64 + lane])*sc + sh) * w2v;
      #pragma unroll
      for (int o = 32; o; o >>= 1) h += __shfl_down(h, o, 64);
      if (lane == 0) out[list[it]] = 1.0f/(1.0f + expf(-(h + kb2[0])));
    }
  }
}

// --------------------------------------------------------------------------
__global__ __launch_bounds__(256) void k_uhead_out(
    const unsigned short* __restrict__ u1, const float* __restrict__ st2048,
    const float* __restrict__ g, const float* __restrict__ b,
    const float* __restrict__ w2, const float* __restrict__ b2,
    const int* __restrict__ nbr, const float* __restrict__ s3p,
    float* __restrict__ out){
  __shared__ float sSc[128], sSh[128], sW2[128];
  int tid = threadIdx.x;
  if (blockIdx.x >= 2500){
    int i = (blockIdx.x - 2500)*256 + tid;     // < 320000
    if (i < NPTS) out[i] = s3p[0];
    int4 v = ((const int4*)nbr)[i];
    ((float4*)(out + 2*NPTS))[i] =
        make_float4((float)v.x,(float)v.y,(float)v.z,(float)v.w);
    return;
  }
  if (tid < 128){
    float su = st2048[tid], sq = st2048[128+tid];
    float mean = su*INV_N, var = sq*INV_N - mean*mean;
    float sc = g[tid]*rsqrtf(var+BNEPS);
    sSc[tid] = sc; sSh[tid] = b[tid] - mean*sc;
    sW2[tid] = w2[tid];
  }
  __syncthreads();
  int lane = tid & 63, w = tid >> 6;
  for (int n = blockIdx.x*4 + w; n < NPTS; n += 10000){
    unsigned int v = *(const unsigned int*)(u1 + (size_t)n*128 + lane*2);
    int c0 = lane*2, c1 = c0 + 1;
    float h = lrelu(bf2f((unsigned short)(v & 0xffff))*sSc[c0] + sSh[c0])*sW2[c0]
            + lrelu(bf2f((unsigned short)(v >> 16))*sSc[c1] + sSh[c1])*sW2[c1];
    #pragma unroll
    for (int o = 32; o; o >>= 1) h += __shfl_down(h, o, 64);
    if (lane == 0) out[NPTS + n] = 1.0f/(1.0f + expf(-(h + b2[0])));
  }
}

// --------------------------------------------------------------------------
extern "C" void kernel_launch(void* const* d_in, const int* in_sizes, int n_in,
                              void* d_out, int out_size, void* d_ws, size_t ws_size,
                              hipStream_t stream) {
  const float* pts    = (const float*)d_in[0];
  const float* cov    = (const float*)d_in[1];
  const int*   nbr    = (const int*)  d_in[2];
  const float* pre_w  = (const float*)d_in[3];
  const float* pre_b  = (const float*)d_in[4];
  const float* pre_g  = (const float*)d_in[5];
  const float* pre_bb = (const float*)d_in[6];
  const float* kp     = (const float*)d_in[7];
  const float* kpw    = (const float*)d_in[8];
  const float* pos_w1 = (const float*)d_in[9];
  const float* pos_b1 = (const float*)d_in[10];
  const float* pos_g1 = (const float*)d_in[11];
  const float* pos_bb1= (const float*)d_in[12];
  const float* pos_w2 = (const float*)d_in[13];
  const float* pos_b2 = (const float*)d_in[14];
  const float* pos_g2 = (const float*)d_in[15];
  const float* pos_bb2= (const float*)d_in[16];
  const float* agg_w1 = (const float*)d_in[17];
  const float* agg_b1 = (const float*)d_in[18];
  const float* agg_g1 = (const float*)d_in[19];
  const float* agg_bb1= (const float*)d_in[20];
  const float* agg_w2 = (const float*)d_in[21];
  const float* agg_b2 = (const float*)d_in[22];
  const float* agg_g2 = (const float*)d_in[23];
  const float* agg_bb2= (const float*)d_in[24];
  const float* keep_w1= (const float*)d_in[25];
  const float* keep_b1= (const float*)d_in[26];
  const float* keep_g = (const float*)d_in[27];
  const float* keep_bb= (const float*)d_in[28];
  const float* keep_w2= (const float*)d_in[29];
  const float* keep_b2= (const float*)d_in[30];
  const float* uniq_w1= (const float*)d_in[31];
  const float* uniq_b1= (const float*)d_in[32];
  const float* uniq_g = (const float*)d_in[33];
  const float* uniq_bb= (const float*)d_in[34];
  const float* uniq_w2= (const float*)d_in[35];
  const float* uniq_b2= (const float*)d_in[36];

  float* out = (float*)d_out;

  // ---- ws layout ----
  char* wsb = (char*)d_ws;
  size_t off = 0;
  float* stats = (float*)(wsb + off); off += 8192*4;
  int*   gcount = (int*)(stats + 2304);
  float* s3     = stats + 2305;
  float* mom    = stats + 2320;
  float* v2     = stats + 2384;
  float* v3     = stats + 2640;
  float* ub_eff = stats + 2704;
  float* pm     = stats + 2832;              // 2144 floats (X moments)
  float* U      = (float*)(wsb + off); off += 16384*4;
  float* partials  = (float*)(wsb + off); off += (size_t)625*2144*4; // 5.36MB
  float* partials2 = (float*)(wsb + off); off += (size_t)25*2144*4;  // 214KB
  unsigned short* wT = (unsigned short*)(wsb + off); off += (size_t)442368*2;
  unsigned short* kpwT   = wT;
  unsigned short* aggw1T = wT + 262144;
  unsigned short* aggw2T = wT + 294912;
  unsigned short* keepw1T= wT + 360448;
  unsigned short* uniqw1T= wT + 376832;
  unsigned short* posw2B = (unsigned short*)(wsb + off); off += (size_t)16384*2;
  unsigned short* uw1B   = (unsigned short*)(wsb + off); off += (size_t)32768*2;
  float* fsum = (float*)(wsb + off); off += (size_t)NPTS*4;
  float* invn = (float*)(wsb + off); off += (size_t)NPTS*4;
  int*   list = (int*)  (wsb + off); off += (size_t)NPTS*4;
  unsigned short* feat = (unsigned short*)(wsb + off); off += (size_t)NPTS*128*2;
  unsigned short* kpfc = (unsigned short*)(wsb + off); off += (size_t)NPTS*128*2;
  unsigned short* a1c  = (unsigned short*)(wsb + off); off += (size_t)NPTS*256*2;
  unsigned short* a2c  = (unsigned short*)(wsb + off); off += (size_t)NPTS*256*2;
  unsigned short* k1c  = (unsigned short*)(wsb + off); off += (size_t)NPTS*64*2;
  unsigned short* u1   = (unsigned short*)(wsb + off); off += (size_t)NPTS*128*2;

  const double kpe = 1.0 / (cbrt(15.0) - 1.0) * 1.5;   // KP_EXTENT
  const float inv_ext = (float)(1.0 / kpe);
  const float ext2 = (float)(kpe * kpe);

  hipMemsetAsync(stats, 0, 2832*sizeof(float), stream);

  // prep: transposes + frag-pack + input moments
  k_prep<<<2080, 256, 0, stream>>>(kpw, pos_w2, agg_w1, agg_w2, keep_w1,
                                   uniq_w1, wT, posw2B, uw1B, cov, pts, mom);
  k_bnsetup<<<1, 256, 0, stream>>>(pre_w, pre_b, pre_g, pre_bb,
                                   pos_w1, pos_b1, pos_g1, pos_bb1, stats);
  k_feat<<<2500, 256, 0, stream>>>(cov, pre_w, stats, feat, fsum);
  k_scan<<<5000, 256, 0, stream>>>(pts, nbr, kp, fsum, invn, list, gcount, ext2);
  k_conv_act<<<1024, 256, 0, stream>>>(pts, nbr, kp, feat, kpwT, invn,
                                       list, gcount, kpfc, ext2, inv_ext);

  // pos-branch closed-form bn2 (3-stage deterministic moments)
  k_posmom1<<<625, 256, 0, stream>>>(pts, pos_w1, stats, partials);
  k_posmom2a<<<dim3(9, 25), 256, 0, stream>>>(partials, partials2);
  k_posmom2b<<<9, 256, 0, stream>>>(partials2, pm);
  k_posbn2a<<<64, 256, 0, stream>>>(pm, pos_w2, U);
  k_posbn2b<<<1, 256, 0, stream>>>(pm, U, pos_w2, pos_b2, pos_g2, pos_bb2, stats);

  // sparse agg chain
  k_rowgemm<<<256, 256, 0, stream>>>(kpfc, nullptr, nullptr, nullptr, 128, 0,
                                     aggw1T, agg_b1, 256, a1c, stats + 896,
                                     list, gcount);
  k_const1<<<1, 256, 0, stream>>>(agg_b1, agg_g1, agg_bb1, aggw2T, agg_b2,
                                  stats + 896, v2, gcount);
  k_rowgemm<<<256, 256, 0, stream>>>(a1c, stats + 896, agg_g1, agg_bb1, 256, 1,
                                     aggw2T, agg_b2, 256, a2c, stats + 1408,
                                     list, gcount);
  k_const2<<<1, 256, 0, stream>>>(v2, agg_g2, agg_bb2, keepw1T, keep_b1,
                                  uniqw1T, uniq_b1, stats + 1408, v3, ub_eff,
                                  gcount);
  k_rowgemm<<<256, 256, 0, stream>>>(a2c, stats + 1408, agg_g2, agg_bb2, 256, 1,
                                     keepw1T, keep_b1, 64, k1c, stats + 1920,
                                     list, gcount);
  k_const3<<<1, 64, 0, stream>>>(v3, keep_g, keep_bb, keep_w2, keep_b2,
                                 stats + 1920, s3, gcount);

  // uniq: fused pts->X->p2->bn2->u1; then active delta + keepact
  k_ufused<<<625, 256, 0, stream>>>(pts, pos_w1, stats, posw2B, uw1B,
                                    ub_eff, u1, stats + 2048);
  k_udelta_keep<<<160, 256, 0, stream>>>(a2c, stats + 1408, agg_g2, agg_bb2,
                                         uniqw1T, uniq_b1, ub_eff, u1,
                                         stats + 2048, k1c, stats + 1920,
                                         keep_g, keep_bb, keep_w2, keep_b2,
                                         out, list, gcount);
  // uhead + match-fill + idx passthrough
  k_uhead_out<<<3750, 256, 0, stream>>>(u1, stats + 2048, uniq_g, uniq_bb,
                                        uniq_w2, uniq_b2, nbr, s3, out);
}